// Round 7
// baseline (693.228 us; speedup 1.0000x reference)
//
#include <hip/hip_runtime.h>
#include <math.h>

typedef __bf16 bf16x8 __attribute__((ext_vector_type(8)));
typedef float f32x4 __attribute__((ext_vector_type(4)));

// ---------------- bf16 helpers ----------------
__device__ __forceinline__ unsigned short f2bf(float f) {
    unsigned u = __float_as_uint(f);
    return (unsigned short)((u + 0x7fffu + ((u >> 16) & 1u)) >> 16);
}
__device__ __forceinline__ float2 bf2(unsigned u) {
    float2 r;
    r.x = __uint_as_float(u << 16);
    r.y = __uint_as_float(u & 0xffff0000u);
    return r;
}

// ---------------- prep: x -> bf16 ----------------
__global__ __launch_bounds__(256) void convert_x(
    const float* __restrict__ x, unsigned short* __restrict__ xb, int total)
{
    int g = blockIdx.x * blockDim.x + threadIdx.x;
    if (g < total) xb[g] = f2bf(x[g]);
}

// ---------------- prep: 640-col transposed bf16 weights + folded bias ----------------
// Output-column order == final P position (kv interleave baked in):
//   p in [0,256): cc = 2*(p>>2)+(p&1), W = (p&2)?Wv:Wk, +be folded.
//   [256,384)=q (Wq,bq); [384,512)=s (Ws,bs);
//   [512,640): qWe fused cols: Wt[c][d] = sum_i Wq[d,h*C+i]*We[kk*128+h*C+i].
__global__ __launch_bounds__(256) void prep_w(
    const float* __restrict__ Wq, const float* __restrict__ bq,
    const float* __restrict__ Wk, const float* __restrict__ bk,
    const float* __restrict__ Wv, const float* __restrict__ bv,
    const float* __restrict__ be,
    const float* __restrict__ Ws, const float* __restrict__ bs,
    const float* __restrict__ We, int H,
    unsigned short* __restrict__ Wt, float* __restrict__ bias)
{
    int g = blockIdx.x * blockDim.x + threadIdx.x;
    const int C = 128 / H;
    if (g < 640) {
        int p = g;
        float b;
        if (p < 256) {
            int cc = 2 * (p >> 2) + (p & 1);
            b = ((p & 2) ? bv[cc] : bk[cc]) + be[cc];
        }
        else if (p < 384) b = bq[p - 256];
        else if (p < 512) b = bs[p - 384];
        else {
            int c2 = p - 512, h = c2 >> 4, kk = c2 & 15;
            b = 0.f;
            if (h < H) for (int i = 0; i < C; ++i) b += bq[h * C + i] * We[kk * 128 + h * C + i];
        }
        bias[p] = b;
    }
    if (g >= 640 * 128) return;
    int p = g >> 7, d = g & 127;
    float w;
    if (p < 256) {
        int cc = 2 * (p >> 2) + (p & 1);
        w = (p & 2) ? Wv[d * 128 + cc] : Wk[d * 128 + cc];
    } else if (p < 384) {
        w = Wq[d * 128 + (p - 256)];
    } else if (p < 512) {
        w = Ws[d * 128 + (p - 384)];
    } else {
        int c2 = p - 512, h = c2 >> 4, kk = c2 & 15;
        w = 0.f;
        if (h < H) for (int i = 0; i < C; ++i) w += Wq[d * 128 + h * C + i] * We[kk * 128 + h * C + i];
    }
    Wt[(size_t)p * 128 + d] = f2bf(w);
}

// ---------------- MFMA bf16 GEMM: [P | qWe] = Xb[m,128] @ Wt + bias ----------------
// Round-0 structure (2D grid). B tile (64 cols x 128 k, 16 KB) staged in
// LDS. C-frag: col=lane&15, row=(lane>>4)*4+reg [m89/m91]. Epilogue via
// LDS for coalesced stores.
__global__ __launch_bounds__(256) void gemm_bf16(
    const unsigned short* __restrict__ Xb, int M,
    const unsigned short* __restrict__ Wt, const float* __restrict__ bias,
    unsigned short* __restrict__ P, float* __restrict__ qWe)
{
    __shared__ unsigned short Bs[64][136];
    __shared__ unsigned short tile[4][16][64];
    const int wv = threadIdx.x >> 6, lane = threadIdx.x & 63;
    const int row0 = blockIdx.x * 64 + wv * 16;
    const int n0 = blockIdx.y * 64;                 // [0,640)
    const int quad = lane >> 4, l16 = lane & 15;

    {   // stage Wt column-tile into LDS: 1024 x uint4, coalesced
        const uint4* gsrc = (const uint4*)(Wt + (size_t)n0 * 128);
#pragma unroll
        for (int u = 0; u < 4; ++u) {
            int v = threadIdx.x + u * 256;
            int col = v >> 4, k8 = v & 15;
            *(uint4*)(&Bs[col][k8 * 8]) = gsrc[v];
        }
    }
    __syncthreads();

    f32x4 acc[4] = {};
    int mrow = row0 + l16; if (mrow >= M) mrow = M - 1;  // clamp loads; stores guarded
    const int kb = quad * 8;
#pragma unroll
    for (int kk = 0; kk < 4; ++kk) {
        bf16x8 a = *(const bf16x8*)(Xb + (size_t)mrow * 128 + kk * 32 + kb);
#pragma unroll
        for (int f = 0; f < 4; ++f) {
            bf16x8 b = *(const bf16x8*)(&Bs[f * 16 + l16][kk * 32 + kb]);
            acc[f] = __builtin_amdgcn_mfma_f32_16x16x32_bf16(a, b, acc[f], 0, 0, 0);
        }
    }
    if (n0 < 512) {
#pragma unroll
        for (int f = 0; f < 4; ++f) {
            float bs = bias[n0 + f * 16 + l16];
#pragma unroll
            for (int r = 0; r < 4; ++r) {
                int row = quad * 4 + r;
                int col = f * 16 + l16;
                tile[wv][row][col ^ ((row & 3) << 4)] = f2bf(acc[f][r] + bs);
            }
        }
        __syncthreads();
        int row = lane >> 2, seg = lane & 3;
        int m = row0 + row;
        if (m < M) {
            const uint4* src = (const uint4*)&tile[wv][row][(seg ^ (row & 3)) << 4];
            uint4* dst = (uint4*)(P + (size_t)m * 512 + n0 + seg * 16);
            dst[0] = src[0];
            dst[1] = src[1];
        }
    } else {
#pragma unroll
        for (int f = 0; f < 4; ++f) {
            int c = n0 + f * 16 + l16;
            float bs = bias[c];
#pragma unroll
            for (int r = 0; r < 4; ++r) {
                int m = row0 + quad * 4 + r;
                if (m < M) qWe[(size_t)m * 128 + (c - 512)] = acc[f][r] + bs;
            }
        }
    }
}

// ---------------- CSR build (int atomics only) ----------------
__global__ __launch_bounds__(256) void degree_kernel(
    const int* __restrict__ ei, int* __restrict__ deg, int E)
{
    int e = blockIdx.x * blockDim.x + threadIdx.x;
    if (e < E) atomicAdd(&deg[ei[E + e]], 1);
}

__global__ __launch_bounds__(1024) void scan_kernel(
    const int* __restrict__ deg, int* __restrict__ rowptr,
    int* __restrict__ cursor, int N)
{
    __shared__ int sums[1024];
    const int T = 1024;
    const int C = (N + T - 1) / T;
    const int t = threadIdx.x;
    const int b0 = t * C;
    int s = 0;
    for (int i = 0; i < C; ++i) { int idx = b0 + i; if (idx < N) s += deg[idx]; }
    sums[t] = s;
    __syncthreads();
    for (int ofs = 1; ofs < 1024; ofs <<= 1) {
        int v = (t >= ofs) ? sums[t - ofs] : 0;
        __syncthreads();
        sums[t] += v;
        __syncthreads();
    }
    int run = (t == 0) ? 0 : sums[t - 1];
    if (t == 0) rowptr[0] = 0;
    for (int i = 0; i < C; ++i) {
        int idx = b0 + i;
        if (idx < N) {
            int d = deg[idx];
            cursor[idx] = run;
            run += d;
            rowptr[idx + 1] = run;
        }
    }
}

__global__ __launch_bounds__(256) void scatter_kernel(
    const int* __restrict__ ei, int* __restrict__ cursor,
    int2* __restrict__ csr, int E)
{
    int e = blockIdx.x * blockDim.x + threadIdx.x;
    if (e < E) {
        int pos = atomicAdd(&cursor[ei[E + e]], 1);
        csr[pos] = make_int2(ei[e], e);   // (src, edge id)
    }
}

// ---------------- fused score + online-softmax + aggregation ----------------
// 32 lanes per node slice, TWO edges per wave instruction. Lane covers 4
// channels (uint4 = k2|v2|k2|v2); half = lane>>5 handles edge parity.
// 16-edge chunks: loads-only gather phase (8 kv + 8 ea in flight),
// then score/softmax/accumulate. Halves combined via xor-32 in the epilogue.
//
// ROUND 7: 512-thread blocks (8 waves/block). r6 showed 4-wave one-shot
// blocks win (138 µs) but occupancy is only 27% (~2.2 blocks/CU resident):
// the CP's block placement rate (~200 blocks/µs) can't keep 7 small blocks
// per CU in flight. 8-wave blocks halve the required placement rate; VGPR
// 72 permits 3 blocks/CU = 24 waves/CU. Per-wave code unchanged.
__global__ __launch_bounds__(512) void fused1_node(
    const unsigned short* __restrict__ P, const float* __restrict__ qWe,
    const float* __restrict__ ea, const float* __restrict__ We1,
    const int2* __restrict__ csr, const int* __restrict__ rowptr,
    unsigned short* __restrict__ h1, int N)
{
    const int lane = threadIdx.x & 63;
    const int node = blockIdx.x * 8 + (threadIdx.x >> 6);
    if (node >= N) return;
    const int l32 = lane & 31, half = lane >> 5;
    const int sub4 = l32 & 3;
    const int c0 = l32 * 4;
    const int hsrc = (lane & 32) | (l32 & 28);   // my half's slot-owner base for my head

    const int beg = rowptr[node];
    const int deg = rowptr[node + 1] - beg;

    uint2 su = *(const uint2*)(P + (size_t)node * 512 + 384 + c0);
    float2 ska = bf2(su.x), skb = bf2(su.y);
    if (deg == 0) {
        if (half == 0) {
            float o0 = ska.x > 0.f ? ska.x : 0.01f * ska.x;
            float o1 = ska.y > 0.f ? ska.y : 0.01f * ska.y;
            float o2 = skb.x > 0.f ? skb.x : 0.01f * skb.x;
            float o3 = skb.y > 0.f ? skb.y : 0.01f * skb.y;
            uint2 pk;
            pk.x = (unsigned)f2bf(o0) | ((unsigned)f2bf(o1) << 16);
            pk.y = (unsigned)f2bf(o2) | ((unsigned)f2bf(o3) << 16);
            *(uint2*)(h1 + (size_t)node * 128 + c0) = pk;
        }
        return;
    }

    uint2 qu = *(const uint2*)(P + (size_t)node * 512 + 256 + c0);
    float2 qa = bf2(qu.x), qb = bf2(qu.y);
    float4 qw4 = *(const float4*)(qWe + (size_t)node * 128 + c0);

    float4 acc = make_float4(0.f, 0.f, 0.f, 0.f);
    float4 A2  = make_float4(0.f, 0.f, 0.f, 0.f);
    float m = -INFINITY, lden = 0.f;

    int2 se = make_int2(0, 0);
    if (lane < deg) se = csr[beg + lane];

    for (int blk = 0; blk < deg; blk += 64) {
        if (blk) se = (blk + lane < deg) ? csr[beg + blk + lane] : make_int2(0, 0);
        const int bcnt = min(64, deg - blk);
        for (int cb = 0; cb < bcnt; cb += 16) {
            const int lim = min(16, bcnt - cb);
            uint4 kv[8]; float4 ea4[8];
            // ---- gather phase: loads only, up to 16 in flight ----
#pragma unroll
            for (int i = 0; i < 8; ++i) {
                if (2 * i < lim) {   // wave-uniform
                    int jj = cb + 2 * i + half;
                    int jc = min(jj, bcnt - 1);
                    int sb = __shfl(se.x, jc, 64);
                    int eb = __shfl(se.y, jc, 64);
                    kv[i]  = *(const uint4*)(P + (size_t)sb * 512 + l32 * 8);
                    ea4[i] = *(const float4*)(ea + (size_t)eb * 16 + sub4 * 4);
                }
            }
            // ---- score phase ----
            float s0 = -INFINITY, s1 = -INFINITY;
#pragma unroll
            for (int i = 0; i < 8; ++i) {
                if (2 * i < lim) {
                    float2 ka = bf2(kv[i].x), kb = bf2(kv[i].z);
                    float p = qa.x * ka.x + qa.y * ka.y + qb.x * kb.x + qb.y * kb.y
                            + qw4.x * ea4[i].x + qw4.y * ea4[i].y
                            + qw4.z * ea4[i].z + qw4.w * ea4[i].w;
                    p += __shfl_xor(p, 1, 64);
                    p += __shfl_xor(p, 2, 64);    // 4-lane head group
                    bool valid = (cb + 2 * i + half) < bcnt;
                    float pv = valid ? p * 0.25f : -INFINITY;   // 1/sqrt(16)
                    if (sub4 == (i & 3)) { if (i < 4) s0 = pv; else s1 = pv; }
                }
            }
            // ---- online softmax update (per head, across halves) ----
            float cm = fmaxf(s0, s1);
            cm = fmaxf(cm, __shfl_xor(cm, 1, 64));
            cm = fmaxf(cm, __shfl_xor(cm, 2, 64));
            cm = fmaxf(cm, __shfl_xor(cm, 32, 64));
            float m_new = fmaxf(m, cm);
            float scale = __expf(m - m_new);      // first chunk: exp(-inf)=0
            float e0 = __expf(s0 - m_new);        // unassigned slots: 0
            float e1 = __expf(s1 - m_new);
            float ds = e0 + e1;
            ds += __shfl_xor(ds, 1, 64);
            ds += __shfl_xor(ds, 2, 64);
            ds += __shfl_xor(ds, 32, 64);
            lden = lden * scale + ds;
            acc.x *= scale; acc.y *= scale; acc.z *= scale; acc.w *= scale;
            A2.x  *= scale; A2.y  *= scale; A2.z  *= scale; A2.w  *= scale;
            m = m_new;
            // ---- accumulate phase (my half's edges only) ----
#pragma unroll
            for (int i = 0; i < 8; ++i) {
                if (2 * i < lim) {
                    float w = __shfl((i < 4) ? e0 : e1, hsrc | (i & 3), 64);
                    float2 va = bf2(kv[i].y), vb = bf2(kv[i].w);
                    acc.x += w * va.x; acc.y += w * va.y;
                    acc.z += w * vb.x; acc.w += w * vb.y;
                    A2.x += w * ea4[i].x; A2.y += w * ea4[i].y;
                    A2.z += w * ea4[i].z; A2.w += w * ea4[i].w;
                }
            }
        }
    }
    // combine halves
    acc.x += __shfl_xor(acc.x, 32, 64); acc.y += __shfl_xor(acc.y, 32, 64);
    acc.z += __shfl_xor(acc.z, 32, 64); acc.w += __shfl_xor(acc.w, 32, 64);
    A2.x  += __shfl_xor(A2.x, 32, 64);  A2.y  += __shfl_xor(A2.y, 32, 64);
    A2.z  += __shfl_xor(A2.z, 32, 64);  A2.w  += __shfl_xor(A2.w, 32, 64);

    // expand A_h through We1
    float ex0 = 0.f, ex1 = 0.f, ex2 = 0.f, ex3 = 0.f;
#pragma unroll
    for (int k = 0; k < 16; ++k) {
        float comp = (k & 3) == 0 ? A2.x : (k & 3) == 1 ? A2.y : (k & 3) == 2 ? A2.z : A2.w;
        float ak = __shfl(comp, hsrc | (k >> 2), 64);
        float4 w4 = *(const float4*)(We1 + k * 128 + c0);
        ex0 += ak * w4.x; ex1 += ak * w4.y; ex2 += ak * w4.z; ex3 += ak * w4.w;
    }
    float inv = 1.f / (lden + 1e-16f);
    float o0 = (acc.x + ex0) * inv + ska.x;
    float o1 = (acc.y + ex1) * inv + ska.y;
    float o2 = (acc.z + ex2) * inv + skb.x;
    float o3 = (acc.w + ex3) * inv + skb.y;
    o0 = o0 > 0.f ? o0 : 0.01f * o0;
    o1 = o1 > 0.f ? o1 : 0.01f * o1;
    o2 = o2 > 0.f ? o2 : 0.01f * o2;
    o3 = o3 > 0.f ? o3 : 0.01f * o3;
    if (half == 0) {
        uint2 pk;
        pk.x = (unsigned)f2bf(o0) | ((unsigned)f2bf(o1) << 16);
        pk.y = (unsigned)f2bf(o2) | ((unsigned)f2bf(o3) << 16);
        *(uint2*)(h1 + (size_t)node * 128 + c0) = pk;
    }
}

// Layer 2: H=1, C=128. Half-wave (32-lane) dot per edge; lanes 0..7 of each
// half hold the chunk's scores. Same 8-wave one-shot blocks as fused1_node.
__global__ __launch_bounds__(512) void fused2_node(
    const unsigned short* __restrict__ P, const float* __restrict__ qWe,
    const float* __restrict__ ea, const float* __restrict__ We2,
    const int2* __restrict__ csr, const int* __restrict__ rowptr,
    float* __restrict__ out, int N)
{
    const int lane = threadIdx.x & 63;
    const int node = blockIdx.x * 8 + (threadIdx.x >> 6);
    if (node >= N) return;
    const int l32 = lane & 31, half = lane >> 5;
    const int c0 = l32 * 4;
    const int k16 = lane & 15;

    const int beg = rowptr[node];
    const int deg = rowptr[node + 1] - beg;

    uint2 su = *(const uint2*)(P + (size_t)node * 512 + 384 + c0);
    float2 ska = bf2(su.x), skb = bf2(su.y);
    float* outp = out + (size_t)node * 128 + c0;
    if (deg == 0) {
        if (half == 0) *(float4*)outp = make_float4(ska.x, ska.y, skb.x, skb.y);
        return;
    }

    uint2 qu = *(const uint2*)(P + (size_t)node * 512 + 256 + c0);
    float2 qa = bf2(qu.x), qb = bf2(qu.y);
    float qw = qWe[(size_t)node * 128 + k16];

    float4 acc = make_float4(0.f, 0.f, 0.f, 0.f);
    float accA = 0.f;
    float m = -INFINITY, lden = 0.f;

    int2 se = make_int2(0, 0);
    if (lane < deg) se = csr[beg + lane];

    for (int blk = 0; blk < deg; blk += 64) {
        if (blk) se = (blk + lane < deg) ? csr[beg + blk + lane] : make_int2(0, 0);
        const int bcnt = min(64, deg - blk);
        for (int cb = 0; cb < bcnt; cb += 16) {
            const int lim = min(16, bcnt - cb);
            uint4 kv[8]; float eav[8];
            // ---- gather phase ----
#pragma unroll
            for (int i = 0; i < 8; ++i) {
                if (2 * i < lim) {
                    int jj = cb + 2 * i + half;
                    int jc = min(jj, bcnt - 1);
                    int sb = __shfl(se.x, jc, 64);
                    int eb = __shfl(se.y, jc, 64);
                    kv[i]  = *(const uint4*)(P + (size_t)sb * 512 + l32 * 8);
                    eav[i] = ea[(size_t)eb * 16 + k16];
                }
            }
            // ---- score phase ----
            float my_s = -INFINITY;
#pragma unroll
            for (int i = 0; i < 8; ++i) {
                if (2 * i < lim) {
                    float2 ka = bf2(kv[i].x), kb = bf2(kv[i].z);
                    float p = qa.x * ka.x + qa.y * ka.y + qb.x * kb.x + qb.y * kb.y
                            + 0.5f * qw * eav[i];   // 2x dup within half
                    p += __shfl_xor(p, 1, 64);
                    p += __shfl_xor(p, 2, 64);
                    p += __shfl_xor(p, 4, 64);
                    p += __shfl_xor(p, 8, 64);
                    p += __shfl_xor(p, 16, 64);     // half-wide reduction
                    bool valid = (cb + 2 * i + half) < bcnt;
                    if (l32 == i) my_s = valid ? p * 0.08838834764831845f : -INFINITY;
                }
            }
            // ---- online softmax ----
            float cm = my_s;
#pragma unroll
            for (int mk = 1; mk < 64; mk <<= 1) cm = fmaxf(cm, __shfl_xor(cm, mk, 64));
            float m_new = fmaxf(m, cm);
            float scale = __expf(m - m_new);
            float ew = __expf(my_s - m_new);   // non-slot / invalid: 0
            float ds = ew;
#pragma unroll
            for (int mk = 1; mk < 64; mk <<= 1) ds += __shfl_xor(ds, mk, 64);
            lden = lden * scale + ds;
            acc.x *= scale; acc.y *= scale; acc.z *= scale; acc.w *= scale;
            accA *= scale;
            m = m_new;
            // ---- accumulate (my half's edges) ----
#pragma unroll
            for (int i = 0; i < 8; ++i) {
                if (2 * i < lim) {
                    float w = __shfl(ew, (lane & 32) | i, 64);
                    float2 va = bf2(kv[i].y), vb = bf2(kv[i].w);
                    acc.x += w * va.x; acc.y += w * va.y;
                    acc.z += w * vb.x; acc.w += w * vb.y;
                    accA += w * eav[i];
                }
            }
        }
    }
    // combine halves
    acc.x += __shfl_xor(acc.x, 32, 64); acc.y += __shfl_xor(acc.y, 32, 64);
    acc.z += __shfl_xor(acc.z, 32, 64); acc.w += __shfl_xor(acc.w, 32, 64);
    accA  += __shfl_xor(accA, 32, 64);

    float ex0 = 0.f, ex1 = 0.f, ex2 = 0.f, ex3 = 0.f;
#pragma unroll
    for (int k = 0; k < 16; ++k) {
        float ak = __shfl(accA, (lane & 48) | k, 64);
        float4 w4 = *(const float4*)(We2 + k * 128 + c0);
        ex0 += ak * w4.x; ex1 += ak * w4.y; ex2 += ak * w4.z; ex3 += ak * w4.w;
    }
    float inv = 1.f / (lden + 1e-16f);
    if (half == 0) {
        float4 o;
        o.x = (acc.x + ex0) * inv + ska.x;
        o.y = (acc.y + ex1) * inv + ska.y;
        o.z = (acc.z + ex2) * inv + skb.x;
        o.w = (acc.w + ex3) * inv + skb.y;
        *(float4*)outp = o;
    }
}

// ---------------- launch ----------------
extern "C" void kernel_launch(void* const* d_in, const int* in_sizes, int n_in,
                              void* d_out, int out_size, void* d_ws, size_t ws_size,
                              hipStream_t stream)
{
    const float* x  = (const float*)d_in[0];
    const int*   ei = (const int*)d_in[1];
    const float* ea = (const float*)d_in[2];
    const float *Wq1 = (const float*)d_in[3],  *bq1 = (const float*)d_in[4];
    const float *Wk1 = (const float*)d_in[5],  *bk1 = (const float*)d_in[6];
    const float *Wv1 = (const float*)d_in[7],  *bv1 = (const float*)d_in[8];
    const float *We1 = (const float*)d_in[9],  *be1 = (const float*)d_in[10];
    const float *Ws1 = (const float*)d_in[11], *bs1 = (const float*)d_in[12];
    const float *Wq2 = (const float*)d_in[13], *bq2 = (const float*)d_in[14];
    const float *Wk2 = (const float*)d_in[15], *bk2 = (const float*)d_in[16];
    const float *Wv2 = (const float*)d_in[17], *bv2 = (const float*)d_in[18];
    const float *We2 = (const float*)d_in[19], *be2 = (const float*)d_in[20];
    const float *Ws2 = (const float*)d_in[21], *bs2 = (const float*)d_in[22];

    const int N = in_sizes[0] / 128;
    const int E = in_sizes[1] / 2;

    char* ws = (char*)d_ws;
    size_t off = 0;
    auto alloc = [&](size_t bytes) -> void* {
        void* p = ws + off;
        off = (off + bytes + 255) & ~(size_t)255;
        return p;
    };
    unsigned short* xb  = (unsigned short*)alloc((size_t)N * 128 * 2);
    unsigned short* P   = (unsigned short*)alloc((size_t)N * 512 * 2);  // bf16 [kv-interleave | q | s]
    unsigned short* h1b = (unsigned short*)alloc((size_t)N * 128 * 2);
    unsigned short* Wt1 = (unsigned short*)alloc((size_t)640 * 128 * 2);
    unsigned short* Wt2 = (unsigned short*)alloc((size_t)640 * 128 * 2);
    float* bias1 = (float*)alloc(640 * 4);
    float* bias2 = (float*)alloc(640 * 4);
    float* qWe   = (float*)alloc((size_t)N * 128 * 4);
    int*  deg    = (int*)alloc((size_t)N * 4);
    int*  rowptr = (int*)alloc((size_t)(N + 1) * 4);
    int*  cursor = (int*)alloc((size_t)N * 4);
    int2* csr    = (int2*)alloc((size_t)E * 8);

    dim3 gemm_grid1((N + 63) / 64, 10);
    dim3 gemm_grid2((N + 63) / 64, 9);   // layer-2 qWe needs only cols [512,528)
    const int tn = N * 128;
    const int node_blocks = (N + 7) / 8;     // 8 nodes (8 waves) per 512-thread block
    const int prep_blocks = (640 * 128 + 255) / 256;

    // ---- prep (independent of everything else) ----
    convert_x<<<(tn + 255) / 256, 256, 0, stream>>>(x, xb, tn);
    prep_w<<<prep_blocks, 256, 0, stream>>>(Wq1, bq1, Wk1, bk1, Wv1, bv1, be1, Ws1, bs1, We1, 8, Wt1, bias1);
    prep_w<<<prep_blocks, 256, 0, stream>>>(Wq2, bq2, Wk2, bk2, Wv2, bv2, be2, Ws2, bs2, We2, 1, Wt2, bias2);

    // ---- CSR build (shared by both layers) ----
    hipMemsetAsync(deg, 0, (size_t)N * 4, stream);
    degree_kernel<<<(E + 255) / 256, 256, 0, stream>>>(ei, deg, E);
    scan_kernel<<<1, 1024, 0, stream>>>(deg, rowptr, cursor, N);
    scatter_kernel<<<(E + 255) / 256, 256, 0, stream>>>(ei, cursor, csr, E);

    // ---- layer 1 (H=8, C=16, concat) ----
    gemm_bf16<<<gemm_grid1, 256, 0, stream>>>(xb, N, Wt1, bias1, P, qWe);
    fused1_node<<<node_blocks, 512, 0, stream>>>(P, qWe, ea, We1, csr, rowptr, h1b, N);

    // ---- layer 2 (H=1, C=128, mean==identity) ----
    gemm_bf16<<<gemm_grid2, 256, 0, stream>>>(h1b, N, Wt2, bias2, P, qWe);
    fused2_node<<<node_blocks, 512, 0, stream>>>(P, qWe, ea, We2, csr, rowptr, (float*)d_out, N);
}

// Round 8
// 614.672 us; speedup vs baseline: 1.1278x; 1.1278x over previous
//
#include <hip/hip_runtime.h>
#include <math.h>

typedef __bf16 bf16x8 __attribute__((ext_vector_type(8)));
typedef float f32x4 __attribute__((ext_vector_type(4)));

// ---------------- bf16 helpers ----------------
__device__ __forceinline__ unsigned short f2bf(float f) {
    unsigned u = __float_as_uint(f);
    return (unsigned short)((u + 0x7fffu + ((u >> 16) & 1u)) >> 16);
}
__device__ __forceinline__ float2 bf2(unsigned u) {
    float2 r;
    r.x = __uint_as_float(u << 16);
    r.y = __uint_as_float(u & 0xffff0000u);
    return r;
}

// ---------------- prep: x -> bf16 ----------------
__global__ __launch_bounds__(256) void convert_x(
    const float* __restrict__ x, unsigned short* __restrict__ xb, int total)
{
    int g = blockIdx.x * blockDim.x + threadIdx.x;
    if (g < total) xb[g] = f2bf(x[g]);
}

// ---------------- prep: 640-col transposed bf16 weights + folded bias ----------------
// Output-column order == final P position (kv interleave baked in):
//   p in [0,256): cc = 2*(p>>2)+(p&1), W = (p&2)?Wv:Wk, +be folded.
//   [256,384)=q (Wq,bq); [384,512)=s (Ws,bs);
//   [512,640): qWe fused cols: Wt[c][d] = sum_i Wq[d,h*C+i]*We[kk*128+h*C+i].
__global__ __launch_bounds__(256) void prep_w(
    const float* __restrict__ Wq, const float* __restrict__ bq,
    const float* __restrict__ Wk, const float* __restrict__ bk,
    const float* __restrict__ Wv, const float* __restrict__ bv,
    const float* __restrict__ be,
    const float* __restrict__ Ws, const float* __restrict__ bs,
    const float* __restrict__ We, int H,
    unsigned short* __restrict__ Wt, float* __restrict__ bias)
{
    int g = blockIdx.x * blockDim.x + threadIdx.x;
    const int C = 128 / H;
    if (g < 640) {
        int p = g;
        float b;
        if (p < 256) {
            int cc = 2 * (p >> 2) + (p & 1);
            b = ((p & 2) ? bv[cc] : bk[cc]) + be[cc];
        }
        else if (p < 384) b = bq[p - 256];
        else if (p < 512) b = bs[p - 384];
        else {
            int c2 = p - 512, h = c2 >> 4, kk = c2 & 15;
            b = 0.f;
            if (h < H) for (int i = 0; i < C; ++i) b += bq[h * C + i] * We[kk * 128 + h * C + i];
        }
        bias[p] = b;
    }
    if (g >= 640 * 128) return;
    int p = g >> 7, d = g & 127;
    float w;
    if (p < 256) {
        int cc = 2 * (p >> 2) + (p & 1);
        w = (p & 2) ? Wv[d * 128 + cc] : Wk[d * 128 + cc];
    } else if (p < 384) {
        w = Wq[d * 128 + (p - 256)];
    } else if (p < 512) {
        w = Ws[d * 128 + (p - 384)];
    } else {
        int c2 = p - 512, h = c2 >> 4, kk = c2 & 15;
        w = 0.f;
        if (h < H) for (int i = 0; i < C; ++i) w += Wq[d * 128 + h * C + i] * We[kk * 128 + h * C + i];
    }
    Wt[(size_t)p * 128 + d] = f2bf(w);
}

// ---------------- MFMA bf16 GEMM: [P | qWe] = Xb[m,128] @ Wt + bias ----------------
// Round-0 structure (2D grid). B tile (64 cols x 128 k, 16 KB) staged in
// LDS. C-frag: col=lane&15, row=(lane>>4)*4+reg [m89/m91]. Epilogue via
// LDS for coalesced stores.
__global__ __launch_bounds__(256) void gemm_bf16(
    const unsigned short* __restrict__ Xb, int M,
    const unsigned short* __restrict__ Wt, const float* __restrict__ bias,
    unsigned short* __restrict__ P, float* __restrict__ qWe)
{
    __shared__ unsigned short Bs[64][136];
    __shared__ unsigned short tile[4][16][64];
    const int wv = threadIdx.x >> 6, lane = threadIdx.x & 63;
    const int row0 = blockIdx.x * 64 + wv * 16;
    const int n0 = blockIdx.y * 64;                 // [0,640)
    const int quad = lane >> 4, l16 = lane & 15;

    {   // stage Wt column-tile into LDS: 1024 x uint4, coalesced
        const uint4* gsrc = (const uint4*)(Wt + (size_t)n0 * 128);
#pragma unroll
        for (int u = 0; u < 4; ++u) {
            int v = threadIdx.x + u * 256;
            int col = v >> 4, k8 = v & 15;
            *(uint4*)(&Bs[col][k8 * 8]) = gsrc[v];
        }
    }
    __syncthreads();

    f32x4 acc[4] = {};
    int mrow = row0 + l16; if (mrow >= M) mrow = M - 1;  // clamp loads; stores guarded
    const int kb = quad * 8;
#pragma unroll
    for (int kk = 0; kk < 4; ++kk) {
        bf16x8 a = *(const bf16x8*)(Xb + (size_t)mrow * 128 + kk * 32 + kb);
#pragma unroll
        for (int f = 0; f < 4; ++f) {
            bf16x8 b = *(const bf16x8*)(&Bs[f * 16 + l16][kk * 32 + kb]);
            acc[f] = __builtin_amdgcn_mfma_f32_16x16x32_bf16(a, b, acc[f], 0, 0, 0);
        }
    }
    if (n0 < 512) {
#pragma unroll
        for (int f = 0; f < 4; ++f) {
            float bs = bias[n0 + f * 16 + l16];
#pragma unroll
            for (int r = 0; r < 4; ++r) {
                int row = quad * 4 + r;
                int col = f * 16 + l16;
                tile[wv][row][col ^ ((row & 3) << 4)] = f2bf(acc[f][r] + bs);
            }
        }
        __syncthreads();
        int row = lane >> 2, seg = lane & 3;
        int m = row0 + row;
        if (m < M) {
            const uint4* src = (const uint4*)&tile[wv][row][(seg ^ (row & 3)) << 4];
            uint4* dst = (uint4*)(P + (size_t)m * 512 + n0 + seg * 16);
            dst[0] = src[0];
            dst[1] = src[1];
        }
    } else {
#pragma unroll
        for (int f = 0; f < 4; ++f) {
            int c = n0 + f * 16 + l16;
            float bs = bias[c];
#pragma unroll
            for (int r = 0; r < 4; ++r) {
                int m = row0 + quad * 4 + r;
                if (m < M) qWe[(size_t)m * 128 + (c - 512)] = acc[f][r] + bs;
            }
        }
    }
}

// ---------------- CSR build (int atomics only) ----------------
__global__ __launch_bounds__(256) void degree_kernel(
    const int* __restrict__ ei, int* __restrict__ deg, int E)
{
    int e = blockIdx.x * blockDim.x + threadIdx.x;
    if (e < E) atomicAdd(&deg[ei[E + e]], 1);
}

__global__ __launch_bounds__(1024) void scan_kernel(
    const int* __restrict__ deg, int* __restrict__ rowptr,
    int* __restrict__ cursor, int N)
{
    __shared__ int sums[1024];
    const int T = 1024;
    const int C = (N + T - 1) / T;
    const int t = threadIdx.x;
    const int b0 = t * C;
    int s = 0;
    for (int i = 0; i < C; ++i) { int idx = b0 + i; if (idx < N) s += deg[idx]; }
    sums[t] = s;
    __syncthreads();
    for (int ofs = 1; ofs < 1024; ofs <<= 1) {
        int v = (t >= ofs) ? sums[t - ofs] : 0;
        __syncthreads();
        sums[t] += v;
        __syncthreads();
    }
    int run = (t == 0) ? 0 : sums[t - 1];
    if (t == 0) rowptr[0] = 0;
    for (int i = 0; i < C; ++i) {
        int idx = b0 + i;
        if (idx < N) {
            int d = deg[idx];
            cursor[idx] = run;
            run += d;
            rowptr[idx + 1] = run;
        }
    }
}

__global__ __launch_bounds__(256) void scatter_kernel(
    const int* __restrict__ ei, int* __restrict__ cursor,
    int2* __restrict__ csr, int E)
{
    int e = blockIdx.x * blockDim.x + threadIdx.x;
    if (e < E) {
        int pos = atomicAdd(&cursor[ei[E + e]], 1);
        csr[pos] = make_int2(ei[e], e);   // (src, edge id)
    }
}

// ---------------- fused score + online-softmax + aggregation ----------------
// ROUND 8: ONE NODE PER 32-LANE HALF-WAVE. r0/r6/r7 all pinned at ~300-360
// waves/us launched regardless of block geometry -> fused kernels are bound
// by the SPI wave-launch rate (50000 waves / 350 per us = 143 us = measured).
// Halving the wave count (2 nodes per wave, one per half) attacks that bound
// directly; aggregate edges/instruction unchanged (2). All reductions were
// already half-local (4-lane head groups); the cross-half xor-32 combines
// and the half==0 store guard are deleted. kv[8]/ea4[8] budget unchanged; no
// loop-carried state (r2 lesson).
// Per half: 1 edge per gather instr (32 lanes x 16B = full kv row), 8-edge
// chunks; slot owner sub4==(i&3), slot=i>>2 (unchanged expressions).
__global__ __launch_bounds__(256) void fused1_node(
    const unsigned short* __restrict__ P, const float* __restrict__ qWe,
    const float* __restrict__ ea, const float* __restrict__ We1,
    const int2* __restrict__ csr, const int* __restrict__ rowptr,
    unsigned short* __restrict__ h1, int N)
{
    const int lane = threadIdx.x & 63;
    const int node = blockIdx.x * 8 + (threadIdx.x >> 5);   // one node per half-wave
    if (node >= N) return;
    const int l32 = lane & 31;
    const int hbit = lane & 32;                 // my half's bit for shfl indices
    const int sub4 = l32 & 3;
    const int c0 = l32 * 4;
    const int hsrc = hbit | (l32 & 28);         // my 4-lane head group's base

    const int beg = rowptr[node];
    const int deg = rowptr[node + 1] - beg;

    uint2 su = *(const uint2*)(P + (size_t)node * 512 + 384 + c0);
    float2 ska = bf2(su.x), skb = bf2(su.y);
    if (deg == 0) {
        float o0 = ska.x > 0.f ? ska.x : 0.01f * ska.x;
        float o1 = ska.y > 0.f ? ska.y : 0.01f * ska.y;
        float o2 = skb.x > 0.f ? skb.x : 0.01f * skb.x;
        float o3 = skb.y > 0.f ? skb.y : 0.01f * skb.y;
        uint2 pk;
        pk.x = (unsigned)f2bf(o0) | ((unsigned)f2bf(o1) << 16);
        pk.y = (unsigned)f2bf(o2) | ((unsigned)f2bf(o3) << 16);
        *(uint2*)(h1 + (size_t)node * 128 + c0) = pk;
        return;
    }

    uint2 qu = *(const uint2*)(P + (size_t)node * 512 + 256 + c0);
    float2 qa = bf2(qu.x), qb = bf2(qu.y);
    float4 qw4 = *(const float4*)(qWe + (size_t)node * 128 + c0);

    float4 acc = make_float4(0.f, 0.f, 0.f, 0.f);
    float4 A2  = make_float4(0.f, 0.f, 0.f, 0.f);
    float m = -INFINITY, lden = 0.f;

    int2 se = make_int2(0, 0);
    if (l32 < deg) se = csr[beg + l32];

    for (int blk = 0; blk < deg; blk += 32) {
        if (blk) se = (blk + l32 < deg) ? csr[beg + blk + l32] : make_int2(0, 0);
        const int bcnt = min(32, deg - blk);
        for (int cb = 0; cb < bcnt; cb += 8) {
            const int lim = min(8, bcnt - cb);
            uint4 kv[8]; float4 ea4[8];
            // ---- gather phase: loads only, up to 16 in flight ----
#pragma unroll
            for (int i = 0; i < 8; ++i) {
                if (i < lim) {   // half-uniform
                    int jc = min(cb + i, bcnt - 1);
                    int sb = __shfl(se.x, hbit | jc, 64);
                    int eb = __shfl(se.y, hbit | jc, 64);
                    kv[i]  = *(const uint4*)(P + (size_t)sb * 512 + l32 * 8);
                    ea4[i] = *(const float4*)(ea + (size_t)eb * 16 + sub4 * 4);
                }
            }
            // ---- score phase (edge cb+i; valid iff i<lim) ----
            float s0 = -INFINITY, s1 = -INFINITY;
#pragma unroll
            for (int i = 0; i < 8; ++i) {
                if (i < lim) {
                    float2 ka = bf2(kv[i].x), kb = bf2(kv[i].z);
                    float p = qa.x * ka.x + qa.y * ka.y + qb.x * kb.x + qb.y * kb.y
                            + qw4.x * ea4[i].x + qw4.y * ea4[i].y
                            + qw4.z * ea4[i].z + qw4.w * ea4[i].w;
                    p += __shfl_xor(p, 1, 64);
                    p += __shfl_xor(p, 2, 64);    // 4-lane head group
                    float pv = p * 0.25f;         // 1/sqrt(16)
                    if (sub4 == (i & 3)) { if (i < 4) s0 = pv; else s1 = pv; }
                }
            }
            // ---- online softmax update (per head; half-local) ----
            float cm = fmaxf(s0, s1);
            cm = fmaxf(cm, __shfl_xor(cm, 1, 64));
            cm = fmaxf(cm, __shfl_xor(cm, 2, 64));
            float m_new = fmaxf(m, cm);
            float scale = __expf(m - m_new);      // first chunk: exp(-inf)=0
            float e0 = __expf(s0 - m_new);        // unassigned slots: 0
            float e1 = __expf(s1 - m_new);
            float ds = e0 + e1;
            ds += __shfl_xor(ds, 1, 64);
            ds += __shfl_xor(ds, 2, 64);
            lden = lden * scale + ds;
            acc.x *= scale; acc.y *= scale; acc.z *= scale; acc.w *= scale;
            A2.x  *= scale; A2.y  *= scale; A2.z  *= scale; A2.w  *= scale;
            m = m_new;
            // ---- accumulate phase ----
#pragma unroll
            for (int i = 0; i < 8; ++i) {
                if (i < lim) {
                    float w = __shfl((i < 4) ? e0 : e1, hsrc | (i & 3), 64);
                    float2 va = bf2(kv[i].y), vb = bf2(kv[i].w);
                    acc.x += w * va.x; acc.y += w * va.y;
                    acc.z += w * vb.x; acc.w += w * vb.y;
                    A2.x += w * ea4[i].x; A2.y += w * ea4[i].y;
                    A2.z += w * ea4[i].z; A2.w += w * ea4[i].w;
                }
            }
        }
    }

    // expand A_h through We1 (half-local; no cross-half combine needed)
    float ex0 = 0.f, ex1 = 0.f, ex2 = 0.f, ex3 = 0.f;
#pragma unroll
    for (int k = 0; k < 16; ++k) {
        float comp = (k & 3) == 0 ? A2.x : (k & 3) == 1 ? A2.y : (k & 3) == 2 ? A2.z : A2.w;
        float ak = __shfl(comp, hsrc | (k >> 2), 64);
        float4 w4 = *(const float4*)(We1 + k * 128 + c0);
        ex0 += ak * w4.x; ex1 += ak * w4.y; ex2 += ak * w4.z; ex3 += ak * w4.w;
    }
    float inv = 1.f / (lden + 1e-16f);
    float o0 = (acc.x + ex0) * inv + ska.x;
    float o1 = (acc.y + ex1) * inv + ska.y;
    float o2 = (acc.z + ex2) * inv + skb.x;
    float o3 = (acc.w + ex3) * inv + skb.y;
    o0 = o0 > 0.f ? o0 : 0.01f * o0;
    o1 = o1 > 0.f ? o1 : 0.01f * o1;
    o2 = o2 > 0.f ? o2 : 0.01f * o2;
    o3 = o3 > 0.f ? o3 : 0.01f * o3;
    uint2 pk;
    pk.x = (unsigned)f2bf(o0) | ((unsigned)f2bf(o1) << 16);
    pk.y = (unsigned)f2bf(o2) | ((unsigned)f2bf(o3) << 16);
    *(uint2*)(h1 + (size_t)node * 128 + c0) = pk;
}

// Layer 2: H=1, C=128. One node per 32-lane half; 32-lane dot per edge;
// lanes 0..7 of the half hold the chunk's scores. Same wave-halving as
// fused1_node.
__global__ __launch_bounds__(256) void fused2_node(
    const unsigned short* __restrict__ P, const float* __restrict__ qWe,
    const float* __restrict__ ea, const float* __restrict__ We2,
    const int2* __restrict__ csr, const int* __restrict__ rowptr,
    float* __restrict__ out, int N)
{
    const int lane = threadIdx.x & 63;
    const int node = blockIdx.x * 8 + (threadIdx.x >> 5);
    if (node >= N) return;
    const int l32 = lane & 31;
    const int hbit = lane & 32;
    const int c0 = l32 * 4;
    const int k16 = lane & 15;

    const int beg = rowptr[node];
    const int deg = rowptr[node + 1] - beg;

    uint2 su = *(const uint2*)(P + (size_t)node * 512 + 384 + c0);
    float2 ska = bf2(su.x), skb = bf2(su.y);
    float* outp = out + (size_t)node * 128 + c0;
    if (deg == 0) {
        *(float4*)outp = make_float4(ska.x, ska.y, skb.x, skb.y);
        return;
    }

    uint2 qu = *(const uint2*)(P + (size_t)node * 512 + 256 + c0);
    float2 qa = bf2(qu.x), qb = bf2(qu.y);
    float qw = qWe[(size_t)node * 128 + k16];

    float4 acc = make_float4(0.f, 0.f, 0.f, 0.f);
    float accA = 0.f;
    float m = -INFINITY, lden = 0.f;

    int2 se = make_int2(0, 0);
    if (l32 < deg) se = csr[beg + l32];

    for (int blk = 0; blk < deg; blk += 32) {
        if (blk) se = (blk + l32 < deg) ? csr[beg + blk + l32] : make_int2(0, 0);
        const int bcnt = min(32, deg - blk);
        for (int cb = 0; cb < bcnt; cb += 8) {
            const int lim = min(8, bcnt - cb);
            uint4 kv[8]; float eav[8];
            // ---- gather phase ----
#pragma unroll
            for (int i = 0; i < 8; ++i) {
                if (i < lim) {
                    int jc = min(cb + i, bcnt - 1);
                    int sb = __shfl(se.x, hbit | jc, 64);
                    int eb = __shfl(se.y, hbit | jc, 64);
                    kv[i]  = *(const uint4*)(P + (size_t)sb * 512 + l32 * 8);
                    eav[i] = ea[(size_t)eb * 16 + k16];
                }
            }
            // ---- score phase (32-lane dot within half) ----
            float my_s = -INFINITY;
#pragma unroll
            for (int i = 0; i < 8; ++i) {
                if (i < lim) {
                    float2 ka = bf2(kv[i].x), kb = bf2(kv[i].z);
                    float p = qa.x * ka.x + qa.y * ka.y + qb.x * kb.x + qb.y * kb.y
                            + 0.5f * qw * eav[i];   // 2x dup within half
                    p += __shfl_xor(p, 1, 64);
                    p += __shfl_xor(p, 2, 64);
                    p += __shfl_xor(p, 4, 64);
                    p += __shfl_xor(p, 8, 64);
                    p += __shfl_xor(p, 16, 64);     // half-wide reduction
                    if (l32 == i) my_s = p * 0.08838834764831845f;
                }
            }
            // ---- online softmax (half-local) ----
            float cm = my_s;
#pragma unroll
            for (int mk = 1; mk < 32; mk <<= 1) cm = fmaxf(cm, __shfl_xor(cm, mk, 64));
            float m_new = fmaxf(m, cm);
            float scale = __expf(m - m_new);
            float ew = __expf(my_s - m_new);   // non-slot: 0
            float ds = ew;
#pragma unroll
            for (int mk = 1; mk < 32; mk <<= 1) ds += __shfl_xor(ds, mk, 64);
            lden = lden * scale + ds;
            acc.x *= scale; acc.y *= scale; acc.z *= scale; acc.w *= scale;
            accA *= scale;
            m = m_new;
            // ---- accumulate ----
#pragma unroll
            for (int i = 0; i < 8; ++i) {
                if (i < lim) {
                    float w = __shfl(ew, hbit | i, 64);
                    float2 va = bf2(kv[i].y), vb = bf2(kv[i].w);
                    acc.x += w * va.x; acc.y += w * va.y;
                    acc.z += w * vb.x; acc.w += w * vb.y;
                    accA += w * eav[i];
                }
            }
        }
    }

    float ex0 = 0.f, ex1 = 0.f, ex2 = 0.f, ex3 = 0.f;
#pragma unroll
    for (int k = 0; k < 16; ++k) {
        float ak = __shfl(accA, hbit | k, 64);   // lanes 0..15 of my half hold A[k]
        float4 w4 = *(const float4*)(We2 + k * 128 + c0);
        ex0 += ak * w4.x; ex1 += ak * w4.y; ex2 += ak * w4.z; ex3 += ak * w4.w;
    }
    float inv = 1.f / (lden + 1e-16f);
    float4 o;
    o.x = (acc.x + ex0) * inv + ska.x;
    o.y = (acc.y + ex1) * inv + ska.y;
    o.z = (acc.z + ex2) * inv + skb.x;
    o.w = (acc.w + ex3) * inv + skb.y;
    *(float4*)outp = o;
}

// ---------------- launch ----------------
extern "C" void kernel_launch(void* const* d_in, const int* in_sizes, int n_in,
                              void* d_out, int out_size, void* d_ws, size_t ws_size,
                              hipStream_t stream)
{
    const float* x  = (const float*)d_in[0];
    const int*   ei = (const int*)d_in[1];
    const float* ea = (const float*)d_in[2];
    const float *Wq1 = (const float*)d_in[3],  *bq1 = (const float*)d_in[4];
    const float *Wk1 = (const float*)d_in[5],  *bk1 = (const float*)d_in[6];
    const float *Wv1 = (const float*)d_in[7],  *bv1 = (const float*)d_in[8];
    const float *We1 = (const float*)d_in[9],  *be1 = (const float*)d_in[10];
    const float *Ws1 = (const float*)d_in[11], *bs1 = (const float*)d_in[12];
    const float *Wq2 = (const float*)d_in[13], *bq2 = (const float*)d_in[14];
    const float *Wk2 = (const float*)d_in[15], *bk2 = (const float*)d_in[16];
    const float *Wv2 = (const float*)d_in[17], *bv2 = (const float*)d_in[18];
    const float *We2 = (const float*)d_in[19], *be2 = (const float*)d_in[20];
    const float *Ws2 = (const float*)d_in[21], *bs2 = (const float*)d_in[22];

    const int N = in_sizes[0] / 128;
    const int E = in_sizes[1] / 2;

    char* ws = (char*)d_ws;
    size_t off = 0;
    auto alloc = [&](size_t bytes) -> void* {
        void* p = ws + off;
        off = (off + bytes + 255) & ~(size_t)255;
        return p;
    };
    unsigned short* xb  = (unsigned short*)alloc((size_t)N * 128 * 2);
    unsigned short* P   = (unsigned short*)alloc((size_t)N * 512 * 2);  // bf16 [kv-interleave | q | s]
    unsigned short* h1b = (unsigned short*)alloc((size_t)N * 128 * 2);
    unsigned short* Wt1 = (unsigned short*)alloc((size_t)640 * 128 * 2);
    unsigned short* Wt2 = (unsigned short*)alloc((size_t)640 * 128 * 2);
    float* bias1 = (float*)alloc(640 * 4);
    float* bias2 = (float*)alloc(640 * 4);
    float* qWe   = (float*)alloc((size_t)N * 128 * 4);
    int*  deg    = (int*)alloc((size_t)N * 4);
    int*  rowptr = (int*)alloc((size_t)(N + 1) * 4);
    int*  cursor = (int*)alloc((size_t)N * 4);
    int2* csr    = (int2*)alloc((size_t)E * 8);

    dim3 gemm_grid1((N + 63) / 64, 10);
    dim3 gemm_grid2((N + 63) / 64, 9);   // layer-2 qWe needs only cols [512,528)
    const int tn = N * 128;
    const int node_blocks = (N + 7) / 8;     // 8 nodes (8 half-waves) per 256-thread block
    const int prep_blocks = (640 * 128 + 255) / 256;

    // ---- prep (independent of everything else) ----
    convert_x<<<(tn + 255) / 256, 256, 0, stream>>>(x, xb, tn);
    prep_w<<<prep_blocks, 256, 0, stream>>>(Wq1, bq1, Wk1, bk1, Wv1, bv1, be1, Ws1, bs1, We1, 8, Wt1, bias1);
    prep_w<<<prep_blocks, 256, 0, stream>>>(Wq2, bq2, Wk2, bk2, Wv2, bv2, be2, Ws2, bs2, We2, 1, Wt2, bias2);

    // ---- CSR build (shared by both layers) ----
    hipMemsetAsync(deg, 0, (size_t)N * 4, stream);
    degree_kernel<<<(E + 255) / 256, 256, 0, stream>>>(ei, deg, E);
    scan_kernel<<<1, 1024, 0, stream>>>(deg, rowptr, cursor, N);
    scatter_kernel<<<(E + 255) / 256, 256, 0, stream>>>(ei, cursor, csr, E);

    // ---- layer 1 (H=8, C=16, concat) ----
    gemm_bf16<<<gemm_grid1, 256, 0, stream>>>(xb, N, Wt1, bias1, P, qWe);
    fused1_node<<<node_blocks, 256, 0, stream>>>(P, qWe, ea, We1, csr, rowptr, h1b, N);

    // ---- layer 2 (H=1, C=128, mean==identity) ----
    gemm_bf16<<<gemm_grid2, 256, 0, stream>>>(h1b, N, Wt2, bias2, P, qWe);
    fused2_node<<<node_blocks, 256, 0, stream>>>(P, qWe, ea, We2, csr, rowptr, (float*)d_out, N);
}

// Round 9
// 498.400 us; speedup vs baseline: 1.3909x; 1.2333x over previous
//
#include <hip/hip_runtime.h>
#include <math.h>

typedef __bf16 bf16x8 __attribute__((ext_vector_type(8)));
typedef float f32x4 __attribute__((ext_vector_type(4)));

// ---------------- bf16 helpers ----------------
__device__ __forceinline__ unsigned short f2bf(float f) {
    unsigned u = __float_as_uint(f);
    return (unsigned short)((u + 0x7fffu + ((u >> 16) & 1u)) >> 16);
}
__device__ __forceinline__ float2 bf2(unsigned u) {
    float2 r;
    r.x = __uint_as_float(u << 16);
    r.y = __uint_as_float(u & 0xffff0000u);
    return r;
}

// ---------------- prep: x -> bf16 ----------------
__global__ __launch_bounds__(256) void convert_x(
    const float* __restrict__ x, unsigned short* __restrict__ xb, int total)
{
    int g = blockIdx.x * blockDim.x + threadIdx.x;
    if (g < total) xb[g] = f2bf(x[g]);
}

// ---------------- prep: 640-col transposed bf16 weights + folded bias ----------------
// Output-column order == final P position (kv interleave baked in):
//   p in [0,256): cc = 2*(p>>2)+(p&1), W = (p&2)?Wv:Wk, +be folded.
//   [256,384)=q (Wq,bq); [384,512)=s (Ws,bs);
//   [512,640): qWe fused cols: Wt[c][d] = sum_i Wq[d,h*C+i]*We[kk*128+h*C+i].
__global__ __launch_bounds__(256) void prep_w(
    const float* __restrict__ Wq, const float* __restrict__ bq,
    const float* __restrict__ Wk, const float* __restrict__ bk,
    const float* __restrict__ Wv, const float* __restrict__ bv,
    const float* __restrict__ be,
    const float* __restrict__ Ws, const float* __restrict__ bs,
    const float* __restrict__ We, int H,
    unsigned short* __restrict__ Wt, float* __restrict__ bias)
{
    int g = blockIdx.x * blockDim.x + threadIdx.x;
    const int C = 128 / H;
    if (g < 640) {
        int p = g;
        float b;
        if (p < 256) {
            int cc = 2 * (p >> 2) + (p & 1);
            b = ((p & 2) ? bv[cc] : bk[cc]) + be[cc];
        }
        else if (p < 384) b = bq[p - 256];
        else if (p < 512) b = bs[p - 384];
        else {
            int c2 = p - 512, h = c2 >> 4, kk = c2 & 15;
            b = 0.f;
            if (h < H) for (int i = 0; i < C; ++i) b += bq[h * C + i] * We[kk * 128 + h * C + i];
        }
        bias[p] = b;
    }
    if (g >= 640 * 128) return;
    int p = g >> 7, d = g & 127;
    float w;
    if (p < 256) {
        int cc = 2 * (p >> 2) + (p & 1);
        w = (p & 2) ? Wv[d * 128 + cc] : Wk[d * 128 + cc];
    } else if (p < 384) {
        w = Wq[d * 128 + (p - 256)];
    } else if (p < 512) {
        w = Ws[d * 128 + (p - 384)];
    } else {
        int c2 = p - 512, h = c2 >> 4, kk = c2 & 15;
        w = 0.f;
        if (h < H) for (int i = 0; i < C; ++i) w += Wq[d * 128 + h * C + i] * We[kk * 128 + h * C + i];
    }
    Wt[(size_t)p * 128 + d] = f2bf(w);
}

// ---------------- MFMA bf16 GEMM: [P | qWe] = Xb[m,128] @ Wt + bias ----------------
// Round-0 structure (2D grid). B tile (64 cols x 128 k, 16 KB) staged in
// LDS. C-frag: col=lane&15, row=(lane>>4)*4+reg [m89/m91]. Epilogue via
// LDS for coalesced stores.
__global__ __launch_bounds__(256) void gemm_bf16(
    const unsigned short* __restrict__ Xb, int M,
    const unsigned short* __restrict__ Wt, const float* __restrict__ bias,
    unsigned short* __restrict__ P, float* __restrict__ qWe)
{
    __shared__ unsigned short Bs[64][136];
    __shared__ unsigned short tile[4][16][64];
    const int wv = threadIdx.x >> 6, lane = threadIdx.x & 63;
    const int row0 = blockIdx.x * 64 + wv * 16;
    const int n0 = blockIdx.y * 64;                 // [0,640)
    const int quad = lane >> 4, l16 = lane & 15;

    {   // stage Wt column-tile into LDS: 1024 x uint4, coalesced
        const uint4* gsrc = (const uint4*)(Wt + (size_t)n0 * 128);
#pragma unroll
        for (int u = 0; u < 4; ++u) {
            int v = threadIdx.x + u * 256;
            int col = v >> 4, k8 = v & 15;
            *(uint4*)(&Bs[col][k8 * 8]) = gsrc[v];
        }
    }
    __syncthreads();

    f32x4 acc[4] = {};
    int mrow = row0 + l16; if (mrow >= M) mrow = M - 1;  // clamp loads; stores guarded
    const int kb = quad * 8;
#pragma unroll
    for (int kk = 0; kk < 4; ++kk) {
        bf16x8 a = *(const bf16x8*)(Xb + (size_t)mrow * 128 + kk * 32 + kb);
#pragma unroll
        for (int f = 0; f < 4; ++f) {
            bf16x8 b = *(const bf16x8*)(&Bs[f * 16 + l16][kk * 32 + kb]);
            acc[f] = __builtin_amdgcn_mfma_f32_16x16x32_bf16(a, b, acc[f], 0, 0, 0);
        }
    }
    if (n0 < 512) {
#pragma unroll
        for (int f = 0; f < 4; ++f) {
            float bs = bias[n0 + f * 16 + l16];
#pragma unroll
            for (int r = 0; r < 4; ++r) {
                int row = quad * 4 + r;
                int col = f * 16 + l16;
                tile[wv][row][col ^ ((row & 3) << 4)] = f2bf(acc[f][r] + bs);
            }
        }
        __syncthreads();
        int row = lane >> 2, seg = lane & 3;
        int m = row0 + row;
        if (m < M) {
            const uint4* src = (const uint4*)&tile[wv][row][(seg ^ (row & 3)) << 4];
            uint4* dst = (uint4*)(P + (size_t)m * 512 + n0 + seg * 16);
            dst[0] = src[0];
            dst[1] = src[1];
        }
    } else {
#pragma unroll
        for (int f = 0; f < 4; ++f) {
            int c = n0 + f * 16 + l16;
            float bs = bias[c];
#pragma unroll
            for (int r = 0; r < 4; ++r) {
                int m = row0 + quad * 4 + r;
                if (m < M) qWe[(size_t)m * 128 + (c - 512)] = acc[f][r] + bs;
            }
        }
    }
}

// ---------------- CSR build (int atomics only) ----------------
__global__ __launch_bounds__(256) void degree_kernel(
    const int* __restrict__ ei, int* __restrict__ deg, int E)
{
    int e = blockIdx.x * blockDim.x + threadIdx.x;
    if (e < E) atomicAdd(&deg[ei[E + e]], 1);
}

// ROUND 9: block-parallel 3-phase prefix sum. The old single-block
// scan_kernel was the #1 dispatch (122 us, 0.15% occupancy, two 49-iter
// serial dependent-load loops on one CU). Phases: (1) 256-wide block sums,
// (2) single-block scan of the 256 partials, (3) per-block re-scan + write.
__global__ __launch_bounds__(256) void scan_part1(
    const int* __restrict__ deg, int* __restrict__ partial, int N)
{
    __shared__ int s[256];
    const int t = threadIdx.x;
    const int g = blockIdx.x * 256 + t;
    int v = (g < N) ? deg[g] : 0;
    s[t] = v;
    __syncthreads();
    for (int ofs = 128; ofs > 0; ofs >>= 1) {
        if (t < ofs) s[t] += s[t + ofs];
        __syncthreads();
    }
    if (t == 0) partial[blockIdx.x] = s[0];
}

__global__ __launch_bounds__(256) void scan_part2(
    int* __restrict__ partial)   // 256 entries -> exclusive offsets in-place
{
    __shared__ int s[256];
    const int t = threadIdx.x;
    int v = partial[t];
    s[t] = v;
    __syncthreads();
    for (int ofs = 1; ofs < 256; ofs <<= 1) {
        int u = (t >= ofs) ? s[t - ofs] : 0;
        __syncthreads();
        s[t] += u;
        __syncthreads();
    }
    partial[t] = s[t] - v;   // exclusive
}

__global__ __launch_bounds__(256) void scan_part3(
    const int* __restrict__ deg, const int* __restrict__ offs,
    int* __restrict__ rowptr, int* __restrict__ cursor, int N)
{
    __shared__ int s[256];
    const int t = threadIdx.x;
    const int g = blockIdx.x * 256 + t;
    int v = (g < N) ? deg[g] : 0;
    s[t] = v;
    __syncthreads();
    for (int ofs = 1; ofs < 256; ofs <<= 1) {
        int u = (t >= ofs) ? s[t - ofs] : 0;
        __syncthreads();
        s[t] += u;
        __syncthreads();
    }
    const int incl = s[t];
    const int base = offs[blockIdx.x];
    if (g < N) {
        cursor[g] = base + incl - v;      // exclusive prefix
        rowptr[g + 1] = base + incl;      // inclusive prefix
    }
    if (g == 0) rowptr[0] = 0;
}

__global__ __launch_bounds__(256) void scatter_kernel(
    const int* __restrict__ ei, int* __restrict__ cursor,
    int2* __restrict__ csr, int E)
{
    int e = blockIdx.x * blockDim.x + threadIdx.x;
    if (e < E) {
        int pos = atomicAdd(&cursor[ei[E + e]], 1);
        csr[pos] = make_int2(ei[e], e);   // (src, edge id)
    }
}

// ---------------- fused score + online-softmax + aggregation ----------------
// ONE NODE PER 32-LANE HALF-WAVE (r8 win). r0/r6/r7 all pinned at ~300-360
// waves/us launched regardless of block geometry -> fused kernels are bound
// by the SPI wave-launch rate. Halving the wave count (2 nodes per wave, one
// per half) attacks that bound directly; aggregate edges/instruction
// unchanged (2). All reductions half-local; no loop-carried state (r2).
__global__ __launch_bounds__(256) void fused1_node(
    const unsigned short* __restrict__ P, const float* __restrict__ qWe,
    const float* __restrict__ ea, const float* __restrict__ We1,
    const int2* __restrict__ csr, const int* __restrict__ rowptr,
    unsigned short* __restrict__ h1, int N)
{
    const int lane = threadIdx.x & 63;
    const int node = blockIdx.x * 8 + (threadIdx.x >> 5);   // one node per half-wave
    if (node >= N) return;
    const int l32 = lane & 31;
    const int hbit = lane & 32;                 // my half's bit for shfl indices
    const int sub4 = l32 & 3;
    const int c0 = l32 * 4;
    const int hsrc = hbit | (l32 & 28);         // my 4-lane head group's base

    const int beg = rowptr[node];
    const int deg = rowptr[node + 1] - beg;

    uint2 su = *(const uint2*)(P + (size_t)node * 512 + 384 + c0);
    float2 ska = bf2(su.x), skb = bf2(su.y);
    if (deg == 0) {
        float o0 = ska.x > 0.f ? ska.x : 0.01f * ska.x;
        float o1 = ska.y > 0.f ? ska.y : 0.01f * ska.y;
        float o2 = skb.x > 0.f ? skb.x : 0.01f * skb.x;
        float o3 = skb.y > 0.f ? skb.y : 0.01f * skb.y;
        uint2 pk;
        pk.x = (unsigned)f2bf(o0) | ((unsigned)f2bf(o1) << 16);
        pk.y = (unsigned)f2bf(o2) | ((unsigned)f2bf(o3) << 16);
        *(uint2*)(h1 + (size_t)node * 128 + c0) = pk;
        return;
    }

    uint2 qu = *(const uint2*)(P + (size_t)node * 512 + 256 + c0);
    float2 qa = bf2(qu.x), qb = bf2(qu.y);
    float4 qw4 = *(const float4*)(qWe + (size_t)node * 128 + c0);

    float4 acc = make_float4(0.f, 0.f, 0.f, 0.f);
    float4 A2  = make_float4(0.f, 0.f, 0.f, 0.f);
    float m = -INFINITY, lden = 0.f;

    int2 se = make_int2(0, 0);
    if (l32 < deg) se = csr[beg + l32];

    for (int blk = 0; blk < deg; blk += 32) {
        if (blk) se = (blk + l32 < deg) ? csr[beg + blk + l32] : make_int2(0, 0);
        const int bcnt = min(32, deg - blk);
        for (int cb = 0; cb < bcnt; cb += 8) {
            const int lim = min(8, bcnt - cb);
            uint4 kv[8]; float4 ea4[8];
            // ---- gather phase: loads only, up to 16 in flight ----
#pragma unroll
            for (int i = 0; i < 8; ++i) {
                if (i < lim) {   // half-uniform
                    int jc = min(cb + i, bcnt - 1);
                    int sb = __shfl(se.x, hbit | jc, 64);
                    int eb = __shfl(se.y, hbit | jc, 64);
                    kv[i]  = *(const uint4*)(P + (size_t)sb * 512 + l32 * 8);
                    ea4[i] = *(const float4*)(ea + (size_t)eb * 16 + sub4 * 4);
                }
            }
            // ---- score phase (edge cb+i; valid iff i<lim) ----
            float s0 = -INFINITY, s1 = -INFINITY;
#pragma unroll
            for (int i = 0; i < 8; ++i) {
                if (i < lim) {
                    float2 ka = bf2(kv[i].x), kb = bf2(kv[i].z);
                    float p = qa.x * ka.x + qa.y * ka.y + qb.x * kb.x + qb.y * kb.y
                            + qw4.x * ea4[i].x + qw4.y * ea4[i].y
                            + qw4.z * ea4[i].z + qw4.w * ea4[i].w;
                    p += __shfl_xor(p, 1, 64);
                    p += __shfl_xor(p, 2, 64);    // 4-lane head group
                    float pv = p * 0.25f;         // 1/sqrt(16)
                    if (sub4 == (i & 3)) { if (i < 4) s0 = pv; else s1 = pv; }
                }
            }
            // ---- online softmax update (per head; half-local) ----
            float cm = fmaxf(s0, s1);
            cm = fmaxf(cm, __shfl_xor(cm, 1, 64));
            cm = fmaxf(cm, __shfl_xor(cm, 2, 64));
            float m_new = fmaxf(m, cm);
            float scale = __expf(m - m_new);      // first chunk: exp(-inf)=0
            float e0 = __expf(s0 - m_new);        // unassigned slots: 0
            float e1 = __expf(s1 - m_new);
            float ds = e0 + e1;
            ds += __shfl_xor(ds, 1, 64);
            ds += __shfl_xor(ds, 2, 64);
            lden = lden * scale + ds;
            acc.x *= scale; acc.y *= scale; acc.z *= scale; acc.w *= scale;
            A2.x  *= scale; A2.y  *= scale; A2.z  *= scale; A2.w  *= scale;
            m = m_new;
            // ---- accumulate phase ----
#pragma unroll
            for (int i = 0; i < 8; ++i) {
                if (i < lim) {
                    float w = __shfl((i < 4) ? e0 : e1, hsrc | (i & 3), 64);
                    float2 va = bf2(kv[i].y), vb = bf2(kv[i].w);
                    acc.x += w * va.x; acc.y += w * va.y;
                    acc.z += w * vb.x; acc.w += w * vb.y;
                    A2.x += w * ea4[i].x; A2.y += w * ea4[i].y;
                    A2.z += w * ea4[i].z; A2.w += w * ea4[i].w;
                }
            }
        }
    }

    // expand A_h through We1 (half-local; no cross-half combine needed)
    float ex0 = 0.f, ex1 = 0.f, ex2 = 0.f, ex3 = 0.f;
#pragma unroll
    for (int k = 0; k < 16; ++k) {
        float comp = (k & 3) == 0 ? A2.x : (k & 3) == 1 ? A2.y : (k & 3) == 2 ? A2.z : A2.w;
        float ak = __shfl(comp, hsrc | (k >> 2), 64);
        float4 w4 = *(const float4*)(We1 + k * 128 + c0);
        ex0 += ak * w4.x; ex1 += ak * w4.y; ex2 += ak * w4.z; ex3 += ak * w4.w;
    }
    float inv = 1.f / (lden + 1e-16f);
    float o0 = (acc.x + ex0) * inv + ska.x;
    float o1 = (acc.y + ex1) * inv + ska.y;
    float o2 = (acc.z + ex2) * inv + skb.x;
    float o3 = (acc.w + ex3) * inv + skb.y;
    o0 = o0 > 0.f ? o0 : 0.01f * o0;
    o1 = o1 > 0.f ? o1 : 0.01f * o1;
    o2 = o2 > 0.f ? o2 : 0.01f * o2;
    o3 = o3 > 0.f ? o3 : 0.01f * o3;
    uint2 pk;
    pk.x = (unsigned)f2bf(o0) | ((unsigned)f2bf(o1) << 16);
    pk.y = (unsigned)f2bf(o2) | ((unsigned)f2bf(o3) << 16);
    *(uint2*)(h1 + (size_t)node * 128 + c0) = pk;
}

// Layer 2: H=1, C=128. One node per 32-lane half; 32-lane dot per edge;
// lanes 0..7 of the half hold the chunk's scores.
__global__ __launch_bounds__(256) void fused2_node(
    const unsigned short* __restrict__ P, const float* __restrict__ qWe,
    const float* __restrict__ ea, const float* __restrict__ We2,
    const int2* __restrict__ csr, const int* __restrict__ rowptr,
    float* __restrict__ out, int N)
{
    const int lane = threadIdx.x & 63;
    const int node = blockIdx.x * 8 + (threadIdx.x >> 5);
    if (node >= N) return;
    const int l32 = lane & 31;
    const int hbit = lane & 32;
    const int c0 = l32 * 4;
    const int k16 = lane & 15;

    const int beg = rowptr[node];
    const int deg = rowptr[node + 1] - beg;

    uint2 su = *(const uint2*)(P + (size_t)node * 512 + 384 + c0);
    float2 ska = bf2(su.x), skb = bf2(su.y);
    float* outp = out + (size_t)node * 128 + c0;
    if (deg == 0) {
        *(float4*)outp = make_float4(ska.x, ska.y, skb.x, skb.y);
        return;
    }

    uint2 qu = *(const uint2*)(P + (size_t)node * 512 + 256 + c0);
    float2 qa = bf2(qu.x), qb = bf2(qu.y);
    float qw = qWe[(size_t)node * 128 + k16];

    float4 acc = make_float4(0.f, 0.f, 0.f, 0.f);
    float accA = 0.f;
    float m = -INFINITY, lden = 0.f;

    int2 se = make_int2(0, 0);
    if (l32 < deg) se = csr[beg + l32];

    for (int blk = 0; blk < deg; blk += 32) {
        if (blk) se = (blk + l32 < deg) ? csr[beg + blk + l32] : make_int2(0, 0);
        const int bcnt = min(32, deg - blk);
        for (int cb = 0; cb < bcnt; cb += 8) {
            const int lim = min(8, bcnt - cb);
            uint4 kv[8]; float eav[8];
            // ---- gather phase ----
#pragma unroll
            for (int i = 0; i < 8; ++i) {
                if (i < lim) {
                    int jc = min(cb + i, bcnt - 1);
                    int sb = __shfl(se.x, hbit | jc, 64);
                    int eb = __shfl(se.y, hbit | jc, 64);
                    kv[i]  = *(const uint4*)(P + (size_t)sb * 512 + l32 * 8);
                    eav[i] = ea[(size_t)eb * 16 + k16];
                }
            }
            // ---- score phase (32-lane dot within half) ----
            float my_s = -INFINITY;
#pragma unroll
            for (int i = 0; i < 8; ++i) {
                if (i < lim) {
                    float2 ka = bf2(kv[i].x), kb = bf2(kv[i].z);
                    float p = qa.x * ka.x + qa.y * ka.y + qb.x * kb.x + qb.y * kb.y
                            + 0.5f * qw * eav[i];   // 2x dup within half
                    p += __shfl_xor(p, 1, 64);
                    p += __shfl_xor(p, 2, 64);
                    p += __shfl_xor(p, 4, 64);
                    p += __shfl_xor(p, 8, 64);
                    p += __shfl_xor(p, 16, 64);     // half-wide reduction
                    if (l32 == i) my_s = p * 0.08838834764831845f;
                }
            }
            // ---- online softmax (half-local) ----
            float cm = my_s;
#pragma unroll
            for (int mk = 1; mk < 32; mk <<= 1) cm = fmaxf(cm, __shfl_xor(cm, mk, 64));
            float m_new = fmaxf(m, cm);
            float scale = __expf(m - m_new);
            float ew = __expf(my_s - m_new);   // non-slot: 0
            float ds = ew;
#pragma unroll
            for (int mk = 1; mk < 32; mk <<= 1) ds += __shfl_xor(ds, mk, 64);
            lden = lden * scale + ds;
            acc.x *= scale; acc.y *= scale; acc.z *= scale; acc.w *= scale;
            accA *= scale;
            m = m_new;
            // ---- accumulate ----
#pragma unroll
            for (int i = 0; i < 8; ++i) {
                if (i < lim) {
                    float w = __shfl(ew, hbit | i, 64);
                    float2 va = bf2(kv[i].y), vb = bf2(kv[i].w);
                    acc.x += w * va.x; acc.y += w * va.y;
                    acc.z += w * vb.x; acc.w += w * vb.y;
                    accA += w * eav[i];
                }
            }
        }
    }

    float ex0 = 0.f, ex1 = 0.f, ex2 = 0.f, ex3 = 0.f;
#pragma unroll
    for (int k = 0; k < 16; ++k) {
        float ak = __shfl(accA, hbit | k, 64);   // lanes 0..15 of my half hold A[k]
        float4 w4 = *(const float4*)(We2 + k * 128 + c0);
        ex0 += ak * w4.x; ex1 += ak * w4.y; ex2 += ak * w4.z; ex3 += ak * w4.w;
    }
    float inv = 1.f / (lden + 1e-16f);
    float4 o;
    o.x = (acc.x + ex0) * inv + ska.x;
    o.y = (acc.y + ex1) * inv + ska.y;
    o.z = (acc.z + ex2) * inv + skb.x;
    o.w = (acc.w + ex3) * inv + skb.y;
    *(float4*)outp = o;
}

// ---------------- launch ----------------
extern "C" void kernel_launch(void* const* d_in, const int* in_sizes, int n_in,
                              void* d_out, int out_size, void* d_ws, size_t ws_size,
                              hipStream_t stream)
{
    const float* x  = (const float*)d_in[0];
    const int*   ei = (const int*)d_in[1];
    const float* ea = (const float*)d_in[2];
    const float *Wq1 = (const float*)d_in[3],  *bq1 = (const float*)d_in[4];
    const float *Wk1 = (const float*)d_in[5],  *bk1 = (const float*)d_in[6];
    const float *Wv1 = (const float*)d_in[7],  *bv1 = (const float*)d_in[8];
    const float *We1 = (const float*)d_in[9],  *be1 = (const float*)d_in[10];
    const float *Ws1 = (const float*)d_in[11], *bs1 = (const float*)d_in[12];
    const float *Wq2 = (const float*)d_in[13], *bq2 = (const float*)d_in[14];
    const float *Wk2 = (const float*)d_in[15], *bk2 = (const float*)d_in[16];
    const float *Wv2 = (const float*)d_in[17], *bv2 = (const float*)d_in[18];
    const float *We2 = (const float*)d_in[19], *be2 = (const float*)d_in[20];
    const float *Ws2 = (const float*)d_in[21], *bs2 = (const float*)d_in[22];

    const int N = in_sizes[0] / 128;
    const int E = in_sizes[1] / 2;

    char* ws = (char*)d_ws;
    size_t off = 0;
    auto alloc = [&](size_t bytes) -> void* {
        void* p = ws + off;
        off = (off + bytes + 255) & ~(size_t)255;
        return p;
    };
    unsigned short* xb  = (unsigned short*)alloc((size_t)N * 128 * 2);
    unsigned short* P   = (unsigned short*)alloc((size_t)N * 512 * 2);  // bf16 [kv-interleave | q | s]
    unsigned short* h1b = (unsigned short*)alloc((size_t)N * 128 * 2);
    unsigned short* Wt1 = (unsigned short*)alloc((size_t)640 * 128 * 2);
    unsigned short* Wt2 = (unsigned short*)alloc((size_t)640 * 128 * 2);
    float* bias1 = (float*)alloc(640 * 4);
    float* bias2 = (float*)alloc(640 * 4);
    float* qWe   = (float*)alloc((size_t)N * 128 * 4);
    int*  deg    = (int*)alloc((size_t)N * 4);
    int*  rowptr = (int*)alloc((size_t)(N + 1) * 4);
    int*  cursor = (int*)alloc((size_t)N * 4);
    int*  partial= (int*)alloc(256 * 4);
    int2* csr    = (int2*)alloc((size_t)E * 8);

    dim3 gemm_grid1((N + 63) / 64, 10);
    dim3 gemm_grid2((N + 63) / 64, 9);   // layer-2 qWe needs only cols [512,528)
    const int tn = N * 128;
    const int node_blocks = (N + 7) / 8;     // 8 nodes (8 half-waves) per 256-thread block
    const int prep_blocks = (640 * 128 + 255) / 256;
    const int scan_blocks = (N + 255) / 256; // <=256 required (N<=65536)

    // ---- prep (independent of everything else) ----
    convert_x<<<(tn + 255) / 256, 256, 0, stream>>>(x, xb, tn);
    prep_w<<<prep_blocks, 256, 0, stream>>>(Wq1, bq1, Wk1, bk1, Wv1, bv1, be1, Ws1, bs1, We1, 8, Wt1, bias1);
    prep_w<<<prep_blocks, 256, 0, stream>>>(Wq2, bq2, Wk2, bk2, Wv2, bv2, be2, Ws2, bs2, We2, 1, Wt2, bias2);

    // ---- CSR build (shared by both layers) ----
    hipMemsetAsync(deg, 0, (size_t)N * 4, stream);
    hipMemsetAsync(partial, 0, 256 * 4, stream);
    degree_kernel<<<(E + 255) / 256, 256, 0, stream>>>(ei, deg, E);
    scan_part1<<<scan_blocks, 256, 0, stream>>>(deg, partial, N);
    scan_part2<<<1, 256, 0, stream>>>(partial);
    scan_part3<<<scan_blocks, 256, 0, stream>>>(deg, partial, rowptr, cursor, N);
    scatter_kernel<<<(E + 255) / 256, 256, 0, stream>>>(ei, cursor, csr, E);

    // ---- layer 1 (H=8, C=16, concat) ----
    gemm_bf16<<<gemm_grid1, 256, 0, stream>>>(xb, N, Wt1, bias1, P, qWe);
    fused1_node<<<node_blocks, 256, 0, stream>>>(P, qWe, ea, We1, csr, rowptr, h1b, N);

    // ---- layer 2 (H=1, C=128, mean==identity) ----
    gemm_bf16<<<gemm_grid2, 256, 0, stream>>>(h1b, N, Wt2, bias2, P, qWe);
    fused2_node<<<node_blocks, 256, 0, stream>>>(P, qWe, ea, We2, csr, rowptr, (float*)d_out, N);
}

// Round 10
// 477.802 us; speedup vs baseline: 1.4509x; 1.0431x over previous
//
#include <hip/hip_runtime.h>
#include <math.h>

typedef __bf16 bf16x8 __attribute__((ext_vector_type(8)));
typedef float f32x4 __attribute__((ext_vector_type(4)));

// ---------------- bf16 helpers ----------------
__device__ __forceinline__ unsigned short f2bf(float f) {
    unsigned u = __float_as_uint(f);
    return (unsigned short)((u + 0x7fffu + ((u >> 16) & 1u)) >> 16);
}
__device__ __forceinline__ float2 bf2(unsigned u) {
    float2 r;
    r.x = __uint_as_float(u << 16);
    r.y = __uint_as_float(u & 0xffff0000u);
    return r;
}

// ---------------- prep: x -> bf16 ----------------
__global__ __launch_bounds__(256) void convert_x(
    const float* __restrict__ x, unsigned short* __restrict__ xb, int total)
{
    int g = blockIdx.x * blockDim.x + threadIdx.x;
    if (g < total) xb[g] = f2bf(x[g]);
}

// ---------------- prep: 640-col transposed bf16 weights + folded bias ----------------
// Output-column order == final P position (kv interleave baked in):
//   p in [0,256): cc = 2*(p>>2)+(p&1), W = (p&2)?Wv:Wk, +be folded.
//   [256,384)=q (Wq,bq); [384,512)=s (Ws,bs);
//   [512,640): qWe fused cols: Wt[c][d] = sum_i Wq[d,h*C+i]*We[kk*128+h*C+i].
__global__ __launch_bounds__(256) void prep_w(
    const float* __restrict__ Wq, const float* __restrict__ bq,
    const float* __restrict__ Wk, const float* __restrict__ bk,
    const float* __restrict__ Wv, const float* __restrict__ bv,
    const float* __restrict__ be,
    const float* __restrict__ Ws, const float* __restrict__ bs,
    const float* __restrict__ We, int H,
    unsigned short* __restrict__ Wt, float* __restrict__ bias)
{
    int g = blockIdx.x * blockDim.x + threadIdx.x;
    const int C = 128 / H;
    if (g < 640) {
        int p = g;
        float b;
        if (p < 256) {
            int cc = 2 * (p >> 2) + (p & 1);
            b = ((p & 2) ? bv[cc] : bk[cc]) + be[cc];
        }
        else if (p < 384) b = bq[p - 256];
        else if (p < 512) b = bs[p - 384];
        else {
            int c2 = p - 512, h = c2 >> 4, kk = c2 & 15;
            b = 0.f;
            if (h < H) for (int i = 0; i < C; ++i) b += bq[h * C + i] * We[kk * 128 + h * C + i];
        }
        bias[p] = b;
    }
    if (g >= 640 * 128) return;
    int p = g >> 7, d = g & 127;
    float w;
    if (p < 256) {
        int cc = 2 * (p >> 2) + (p & 1);
        w = (p & 2) ? Wv[d * 128 + cc] : Wk[d * 128 + cc];
    } else if (p < 384) {
        w = Wq[d * 128 + (p - 256)];
    } else if (p < 512) {
        w = Ws[d * 128 + (p - 384)];
    } else {
        int c2 = p - 512, h = c2 >> 4, kk = c2 & 15;
        w = 0.f;
        if (h < H) for (int i = 0; i < C; ++i) w += Wq[d * 128 + h * C + i] * We[kk * 128 + h * C + i];
    }
    Wt[(size_t)p * 128 + d] = f2bf(w);
}

// ---------------- MFMA bf16 GEMM: [P | qWe] = Xb[m,128] @ Wt + bias ----------------
// Round-0 structure (2D grid). B tile (64 cols x 128 k, 16 KB) staged in
// LDS. C-frag: col=lane&15, row=(lane>>4)*4+reg [m89/m91]. Epilogue via
// LDS for coalesced stores.
__global__ __launch_bounds__(256) void gemm_bf16(
    const unsigned short* __restrict__ Xb, int M,
    const unsigned short* __restrict__ Wt, const float* __restrict__ bias,
    unsigned short* __restrict__ P, float* __restrict__ qWe)
{
    __shared__ unsigned short Bs[64][136];
    __shared__ unsigned short tile[4][16][64];
    const int wv = threadIdx.x >> 6, lane = threadIdx.x & 63;
    const int row0 = blockIdx.x * 64 + wv * 16;
    const int n0 = blockIdx.y * 64;                 // [0,640)
    const int quad = lane >> 4, l16 = lane & 15;

    {   // stage Wt column-tile into LDS: 1024 x uint4, coalesced
        const uint4* gsrc = (const uint4*)(Wt + (size_t)n0 * 128);
#pragma unroll
        for (int u = 0; u < 4; ++u) {
            int v = threadIdx.x + u * 256;
            int col = v >> 4, k8 = v & 15;
            *(uint4*)(&Bs[col][k8 * 8]) = gsrc[v];
        }
    }
    __syncthreads();

    f32x4 acc[4] = {};
    int mrow = row0 + l16; if (mrow >= M) mrow = M - 1;  // clamp loads; stores guarded
    const int kb = quad * 8;
#pragma unroll
    for (int kk = 0; kk < 4; ++kk) {
        bf16x8 a = *(const bf16x8*)(Xb + (size_t)mrow * 128 + kk * 32 + kb);
#pragma unroll
        for (int f = 0; f < 4; ++f) {
            bf16x8 b = *(const bf16x8*)(&Bs[f * 16 + l16][kk * 32 + kb]);
            acc[f] = __builtin_amdgcn_mfma_f32_16x16x32_bf16(a, b, acc[f], 0, 0, 0);
        }
    }
    if (n0 < 512) {
#pragma unroll
        for (int f = 0; f < 4; ++f) {
            float bs = bias[n0 + f * 16 + l16];
#pragma unroll
            for (int r = 0; r < 4; ++r) {
                int row = quad * 4 + r;
                int col = f * 16 + l16;
                tile[wv][row][col ^ ((row & 3) << 4)] = f2bf(acc[f][r] + bs);
            }
        }
        __syncthreads();
        int row = lane >> 2, seg = lane & 3;
        int m = row0 + row;
        if (m < M) {
            const uint4* src = (const uint4*)&tile[wv][row][(seg ^ (row & 3)) << 4];
            uint4* dst = (uint4*)(P + (size_t)m * 512 + n0 + seg * 16);
            dst[0] = src[0];
            dst[1] = src[1];
        }
    } else {
#pragma unroll
        for (int f = 0; f < 4; ++f) {
            int c = n0 + f * 16 + l16;
            float bs = bias[c];
#pragma unroll
            for (int r = 0; r < 4; ++r) {
                int m = row0 + quad * 4 + r;
                if (m < M) qWe[(size_t)m * 128 + (c - 512)] = acc[f][r] + bs;
            }
        }
    }
}

// ---------------- CSR build (int atomics only) ----------------
__global__ __launch_bounds__(256) void degree_kernel(
    const int* __restrict__ ei, int* __restrict__ deg, int E)
{
    int e = blockIdx.x * blockDim.x + threadIdx.x;
    if (e < E) atomicAdd(&deg[ei[E + e]], 1);
}

// Block-parallel 3-phase prefix sum (r9 win: replaced 122us single-block scan).
__global__ __launch_bounds__(256) void scan_part1(
    const int* __restrict__ deg, int* __restrict__ partial, int N)
{
    __shared__ int s[256];
    const int t = threadIdx.x;
    const int g = blockIdx.x * 256 + t;
    int v = (g < N) ? deg[g] : 0;
    s[t] = v;
    __syncthreads();
    for (int ofs = 128; ofs > 0; ofs >>= 1) {
        if (t < ofs) s[t] += s[t + ofs];
        __syncthreads();
    }
    if (t == 0) partial[blockIdx.x] = s[0];
}

__global__ __launch_bounds__(256) void scan_part2(
    int* __restrict__ partial)   // 256 entries -> exclusive offsets in-place
{
    __shared__ int s[256];
    const int t = threadIdx.x;
    int v = partial[t];
    s[t] = v;
    __syncthreads();
    for (int ofs = 1; ofs < 256; ofs <<= 1) {
        int u = (t >= ofs) ? s[t - ofs] : 0;
        __syncthreads();
        s[t] += u;
        __syncthreads();
    }
    partial[t] = s[t] - v;   // exclusive
}

__global__ __launch_bounds__(256) void scan_part3(
    const int* __restrict__ deg, const int* __restrict__ offs,
    int* __restrict__ rowptr, int* __restrict__ cursor, int N)
{
    __shared__ int s[256];
    const int t = threadIdx.x;
    const int g = blockIdx.x * 256 + t;
    int v = (g < N) ? deg[g] : 0;
    s[t] = v;
    __syncthreads();
    for (int ofs = 1; ofs < 256; ofs <<= 1) {
        int u = (t >= ofs) ? s[t - ofs] : 0;
        __syncthreads();
        s[t] += u;
        __syncthreads();
    }
    const int incl = s[t];
    const int base = offs[blockIdx.x];
    if (g < N) {
        cursor[g] = base + incl - v;      // exclusive prefix
        rowptr[g + 1] = base + incl;      // inclusive prefix
    }
    if (g == 0) rowptr[0] = 0;
}

__global__ __launch_bounds__(256) void scatter_kernel(
    const int* __restrict__ ei, int* __restrict__ cursor,
    int2* __restrict__ csr, int E)
{
    int e = blockIdx.x * blockDim.x + threadIdx.x;
    if (e < E) {
        int pos = atomicAdd(&cursor[ei[E + e]], 1);
        csr[pos] = make_int2(ei[e], e);   // (src, edge id)
    }
}

// ---------------- fused score + online-softmax + aggregation ----------------
// ROUND 10: ONE NODE PER 16-LANE QUARTER-WAVE. Wave-throughput ledger:
// r6 362 w/us, r7 289, r9 248 -> fused kernels remain wave-supply-bound
// (not VGPR=64, not BW=26%, not VALU=32%). r8's halving won 1.37x; halve
// again: 4 nodes/wave -> 12500 waves. Lane covers 8 channels (32B of kv row
// = 2x uint4); head group = 2-lane pair (1 shfl_xor score reduce); 4-edge
// chunks keep gather regs ~same bytes. Edges per load-inst unchanged (2).
// No loop-carried state (r2 lesson). WATCH: WRITE must stay 12.5 MB (spill
// canary).
__global__ __launch_bounds__(256) void fused1_node(
    const unsigned short* __restrict__ P, const float* __restrict__ qWe,
    const float* __restrict__ ea, const float* __restrict__ We1,
    const int2* __restrict__ csr, const int* __restrict__ rowptr,
    unsigned short* __restrict__ h1, int N)
{
    const int lane = threadIdx.x & 63;
    const int node = blockIdx.x * 16 + (threadIdx.x >> 4);   // one node per quarter
    if (node >= N) return;
    const int l16 = lane & 15;
    const int qbit = lane & 48;       // quarter base (shfl indices)
    const int pbit = lane & 62;       // head-pair base (2 lanes per head)
    const int odd  = lane & 1;        // which ea-feature half this lane owns
    const int c0 = l16 * 8;           // 8 channels per lane

    const int beg = rowptr[node];
    const int deg = rowptr[node + 1] - beg;

    uint4 su = *(const uint4*)(P + (size_t)node * 512 + 384 + c0);
    float2 sk0 = bf2(su.x), sk1 = bf2(su.y), sk2 = bf2(su.z), sk3 = bf2(su.w);
    if (deg == 0) {
        float o0 = sk0.x > 0.f ? sk0.x : 0.01f * sk0.x;
        float o1 = sk0.y > 0.f ? sk0.y : 0.01f * sk0.y;
        float o2 = sk1.x > 0.f ? sk1.x : 0.01f * sk1.x;
        float o3 = sk1.y > 0.f ? sk1.y : 0.01f * sk1.y;
        float o4 = sk2.x > 0.f ? sk2.x : 0.01f * sk2.x;
        float o5 = sk2.y > 0.f ? sk2.y : 0.01f * sk2.y;
        float o6 = sk3.x > 0.f ? sk3.x : 0.01f * sk3.x;
        float o7 = sk3.y > 0.f ? sk3.y : 0.01f * sk3.y;
        uint4 pk;
        pk.x = (unsigned)f2bf(o0) | ((unsigned)f2bf(o1) << 16);
        pk.y = (unsigned)f2bf(o2) | ((unsigned)f2bf(o3) << 16);
        pk.z = (unsigned)f2bf(o4) | ((unsigned)f2bf(o5) << 16);
        pk.w = (unsigned)f2bf(o6) | ((unsigned)f2bf(o7) << 16);
        *(uint4*)(h1 + (size_t)node * 128 + c0) = pk;
        return;
    }

    uint4 qu = *(const uint4*)(P + (size_t)node * 512 + 256 + c0);
    float2 q0 = bf2(qu.x), q1 = bf2(qu.y), q2 = bf2(qu.z), q3 = bf2(qu.w);
    float4 qwA = *(const float4*)(qWe + (size_t)node * 128 + c0);
    float4 qwB = *(const float4*)(qWe + (size_t)node * 128 + c0 + 4);

    float4 acA = make_float4(0.f, 0.f, 0.f, 0.f);   // v accum ch c0..c0+3
    float4 acB = make_float4(0.f, 0.f, 0.f, 0.f);   // v accum ch c0+4..+7
    float4 A2a = make_float4(0.f, 0.f, 0.f, 0.f);   // ea accum kk odd*8..+3
    float4 A2b = make_float4(0.f, 0.f, 0.f, 0.f);   // ea accum kk odd*8+4..+7
    float m = -INFINITY, lden = 0.f;

    int2 se = make_int2(0, 0);
    if (l16 < deg) se = csr[beg + l16];

    for (int blk = 0; blk < deg; blk += 16) {
        if (blk) se = (blk + l16 < deg) ? csr[beg + blk + l16] : make_int2(0, 0);
        const int bcnt = min(16, deg - blk);
        for (int cb = 0; cb < bcnt; cb += 4) {
            const int lim = min(4, bcnt - cb);
            uint4 kva[4], kvb[4]; float4 eaA[4], eaB[4];
            // ---- gather phase: loads only ----
#pragma unroll
            for (int i = 0; i < 4; ++i) {
                if (i < lim) {   // quarter-uniform
                    int jc = min(cb + i, bcnt - 1);
                    int sb = __shfl(se.x, qbit | jc, 64);
                    int eb = __shfl(se.y, qbit | jc, 64);
                    const unsigned short* kp = P + (size_t)sb * 512 + l16 * 16;
                    kva[i] = *(const uint4*)(kp);
                    kvb[i] = *(const uint4*)(kp + 8);
                    const float* ep = ea + (size_t)eb * 16 + odd * 8;
                    eaA[i] = *(const float4*)(ep);
                    eaB[i] = *(const float4*)(ep + 4);
                }
            }
            // ---- score phase ----
            float s0 = -INFINITY, s1 = -INFINITY;
#pragma unroll
            for (int i = 0; i < 4; ++i) {
                if (i < lim) {
                    float2 ka = bf2(kva[i].x), kb = bf2(kva[i].z);
                    float2 kc = bf2(kvb[i].x), kd = bf2(kvb[i].z);
                    float p = q0.x * ka.x + q0.y * ka.y + q1.x * kb.x + q1.y * kb.y
                            + q2.x * kc.x + q2.y * kc.y + q3.x * kd.x + q3.y * kd.y
                            + qwA.x * eaA[i].x + qwA.y * eaA[i].y
                            + qwA.z * eaA[i].z + qwA.w * eaA[i].w
                            + qwB.x * eaB[i].x + qwB.y * eaB[i].y
                            + qwB.z * eaB[i].z + qwB.w * eaB[i].w;
                    p += __shfl_xor(p, 1, 64);    // head-pair sum
                    float pv = p * 0.25f;         // 1/sqrt(16)
                    if (odd == (i & 1)) { if (i < 2) s0 = pv; else s1 = pv; }
                }
            }
            // ---- online softmax update (per head; pair-local) ----
            float cm = fmaxf(s0, s1);
            cm = fmaxf(cm, __shfl_xor(cm, 1, 64));
            float m_new = fmaxf(m, cm);
            float scale = __expf(m - m_new);      // first chunk: exp(-inf)=0
            float e0 = __expf(s0 - m_new);        // unassigned slots: 0
            float e1 = __expf(s1 - m_new);
            float ds = e0 + e1;
            ds += __shfl_xor(ds, 1, 64);
            lden = lden * scale + ds;
            acA.x *= scale; acA.y *= scale; acA.z *= scale; acA.w *= scale;
            acB.x *= scale; acB.y *= scale; acB.z *= scale; acB.w *= scale;
            A2a.x *= scale; A2a.y *= scale; A2a.z *= scale; A2a.w *= scale;
            A2b.x *= scale; A2b.y *= scale; A2b.z *= scale; A2b.w *= scale;
            m = m_new;
            // ---- accumulate phase ----
#pragma unroll
            for (int i = 0; i < 4; ++i) {
                if (i < lim) {
                    float w = __shfl((i < 2) ? e0 : e1, pbit | (i & 1), 64);
                    float2 va = bf2(kva[i].y), vb = bf2(kva[i].w);
                    float2 vc = bf2(kvb[i].y), vd = bf2(kvb[i].w);
                    acA.x += w * va.x; acA.y += w * va.y;
                    acA.z += w * vb.x; acA.w += w * vb.y;
                    acB.x += w * vc.x; acB.y += w * vc.y;
                    acB.z += w * vd.x; acB.w += w * vd.y;
                    A2a.x += w * eaA[i].x; A2a.y += w * eaA[i].y;
                    A2a.z += w * eaA[i].z; A2a.w += w * eaA[i].w;
                    A2b.x += w * eaB[i].x; A2b.y += w * eaB[i].y;
                    A2b.z += w * eaB[i].z; A2b.w += w * eaB[i].w;
                }
            }
        }
    }

    // expand A_h through We1 (pair-local). Lane pbit|(k>>3) holds feature k
    // (component k&7 of its A2a/A2b).
    float ex0 = 0.f, ex1 = 0.f, ex2 = 0.f, ex3 = 0.f;
    float ex4 = 0.f, ex5 = 0.f, ex6 = 0.f, ex7 = 0.f;
#pragma unroll
    for (int k = 0; k < 16; ++k) {
        float comp = (k & 7) == 0 ? A2a.x : (k & 7) == 1 ? A2a.y :
                     (k & 7) == 2 ? A2a.z : (k & 7) == 3 ? A2a.w :
                     (k & 7) == 4 ? A2b.x : (k & 7) == 5 ? A2b.y :
                     (k & 7) == 6 ? A2b.z : A2b.w;
        float ak = __shfl(comp, pbit | (k >> 3), 64);
        const float* wp = We1 + k * 128 + c0;
        float4 w4a = *(const float4*)(wp);
        float4 w4b = *(const float4*)(wp + 4);
        ex0 += ak * w4a.x; ex1 += ak * w4a.y; ex2 += ak * w4a.z; ex3 += ak * w4a.w;
        ex4 += ak * w4b.x; ex5 += ak * w4b.y; ex6 += ak * w4b.z; ex7 += ak * w4b.w;
    }
    float inv = 1.f / (lden + 1e-16f);
    float o0 = (acA.x + ex0) * inv + sk0.x;
    float o1 = (acA.y + ex1) * inv + sk0.y;
    float o2 = (acA.z + ex2) * inv + sk1.x;
    float o3 = (acA.w + ex3) * inv + sk1.y;
    float o4 = (acB.x + ex4) * inv + sk2.x;
    float o5 = (acB.y + ex5) * inv + sk2.y;
    float o6 = (acB.z + ex6) * inv + sk3.x;
    float o7 = (acB.w + ex7) * inv + sk3.y;
    o0 = o0 > 0.f ? o0 : 0.01f * o0;
    o1 = o1 > 0.f ? o1 : 0.01f * o1;
    o2 = o2 > 0.f ? o2 : 0.01f * o2;
    o3 = o3 > 0.f ? o3 : 0.01f * o3;
    o4 = o4 > 0.f ? o4 : 0.01f * o4;
    o5 = o5 > 0.f ? o5 : 0.01f * o5;
    o6 = o6 > 0.f ? o6 : 0.01f * o6;
    o7 = o7 > 0.f ? o7 : 0.01f * o7;
    uint4 pk;
    pk.x = (unsigned)f2bf(o0) | ((unsigned)f2bf(o1) << 16);
    pk.y = (unsigned)f2bf(o2) | ((unsigned)f2bf(o3) << 16);
    pk.z = (unsigned)f2bf(o4) | ((unsigned)f2bf(o5) << 16);
    pk.w = (unsigned)f2bf(o6) | ((unsigned)f2bf(o7) << 16);
    *(uint4*)(h1 + (size_t)node * 128 + c0) = pk;
}

// Layer 2: H=1, C=128. One node per 16-lane quarter; 16-lane dot per edge
// (4 shfl_xor); lanes 0..3 of the quarter hold the chunk's scores. Each ea
// feature appears ONCE in the 16-lane reduce (old half-wave had 2x dup ->
// the 0.5 factor is removed).
__global__ __launch_bounds__(256) void fused2_node(
    const unsigned short* __restrict__ P, const float* __restrict__ qWe,
    const float* __restrict__ ea, const float* __restrict__ We2,
    const int2* __restrict__ csr, const int* __restrict__ rowptr,
    float* __restrict__ out, int N)
{
    const int lane = threadIdx.x & 63;
    const int node = blockIdx.x * 16 + (threadIdx.x >> 4);
    if (node >= N) return;
    const int l16 = lane & 15;
    const int qbit = lane & 48;
    const int c0 = l16 * 8;

    const int beg = rowptr[node];
    const int deg = rowptr[node + 1] - beg;

    uint4 su = *(const uint4*)(P + (size_t)node * 512 + 384 + c0);
    float2 sk0 = bf2(su.x), sk1 = bf2(su.y), sk2 = bf2(su.z), sk3 = bf2(su.w);
    float* outp = out + (size_t)node * 128 + c0;
    if (deg == 0) {
        *(float4*)outp = make_float4(sk0.x, sk0.y, sk1.x, sk1.y);
        *(float4*)(outp + 4) = make_float4(sk2.x, sk2.y, sk3.x, sk3.y);
        return;
    }

    uint4 qu = *(const uint4*)(P + (size_t)node * 512 + 256 + c0);
    float2 q0 = bf2(qu.x), q1 = bf2(qu.y), q2 = bf2(qu.z), q3 = bf2(qu.w);
    float qw = qWe[(size_t)node * 128 + l16];

    float4 acA = make_float4(0.f, 0.f, 0.f, 0.f);
    float4 acB = make_float4(0.f, 0.f, 0.f, 0.f);
    float accA = 0.f;
    float m = -INFINITY, lden = 0.f;

    int2 se = make_int2(0, 0);
    if (l16 < deg) se = csr[beg + l16];

    for (int blk = 0; blk < deg; blk += 16) {
        if (blk) se = (blk + l16 < deg) ? csr[beg + blk + l16] : make_int2(0, 0);
        const int bcnt = min(16, deg - blk);
        for (int cb = 0; cb < bcnt; cb += 4) {
            const int lim = min(4, bcnt - cb);
            uint4 kva[4], kvb[4]; float eav[4];
            // ---- gather phase ----
#pragma unroll
            for (int i = 0; i < 4; ++i) {
                if (i < lim) {
                    int jc = min(cb + i, bcnt - 1);
                    int sb = __shfl(se.x, qbit | jc, 64);
                    int eb = __shfl(se.y, qbit | jc, 64);
                    const unsigned short* kp = P + (size_t)sb * 512 + l16 * 16;
                    kva[i] = *(const uint4*)(kp);
                    kvb[i] = *(const uint4*)(kp + 8);
                    eav[i] = ea[(size_t)eb * 16 + l16];
                }
            }
            // ---- score phase (16-lane dot within quarter) ----
            float my_s = -INFINITY;
#pragma unroll
            for (int i = 0; i < 4; ++i) {
                if (i < lim) {
                    float2 ka = bf2(kva[i].x), kb = bf2(kva[i].z);
                    float2 kc = bf2(kvb[i].x), kd = bf2(kvb[i].z);
                    float p = q0.x * ka.x + q0.y * ka.y + q1.x * kb.x + q1.y * kb.y
                            + q2.x * kc.x + q2.y * kc.y + q3.x * kd.x + q3.y * kd.y
                            + qw * eav[i];
                    p += __shfl_xor(p, 1, 64);
                    p += __shfl_xor(p, 2, 64);
                    p += __shfl_xor(p, 4, 64);
                    p += __shfl_xor(p, 8, 64);     // quarter-wide reduction
                    if (l16 == i) my_s = p * 0.08838834764831845f;  // 1/sqrt(128)
                }
            }
            // ---- online softmax (quarter-local) ----
            float cm = my_s;
#pragma unroll
            for (int mk = 1; mk < 16; mk <<= 1) cm = fmaxf(cm, __shfl_xor(cm, mk, 64));
            float m_new = fmaxf(m, cm);
            float scale = __expf(m - m_new);
            float ew = __expf(my_s - m_new);   // non-slot: 0
            float ds = ew;
#pragma unroll
            for (int mk = 1; mk < 16; mk <<= 1) ds += __shfl_xor(ds, mk, 64);
            lden = lden * scale + ds;
            acA.x *= scale; acA.y *= scale; acA.z *= scale; acA.w *= scale;
            acB.x *= scale; acB.y *= scale; acB.z *= scale; acB.w *= scale;
            accA *= scale;
            m = m_new;
            // ---- accumulate ----
#pragma unroll
            for (int i = 0; i < 4; ++i) {
                if (i < lim) {
                    float w = __shfl(ew, qbit | i, 64);
                    float2 va = bf2(kva[i].y), vb = bf2(kva[i].w);
                    float2 vc = bf2(kvb[i].y), vd = bf2(kvb[i].w);
                    acA.x += w * va.x; acA.y += w * va.y;
                    acA.z += w * vb.x; acA.w += w * vb.y;
                    acB.x += w * vc.x; acB.y += w * vc.y;
                    acB.z += w * vd.x; acB.w += w * vd.y;
                    accA += w * eav[i];
                }
            }
        }
    }

    float ex0 = 0.f, ex1 = 0.f, ex2 = 0.f, ex3 = 0.f;
    float ex4 = 0.f, ex5 = 0.f, ex6 = 0.f, ex7 = 0.f;
#pragma unroll
    for (int k = 0; k < 16; ++k) {
        float ak = __shfl(accA, qbit | k, 64);   // lane qbit+k holds feature k
        const float* wp = We2 + k * 128 + c0;
        float4 w4a = *(const float4*)(wp);
        float4 w4b = *(const float4*)(wp + 4);
        ex0 += ak * w4a.x; ex1 += ak * w4a.y; ex2 += ak * w4a.z; ex3 += ak * w4a.w;
        ex4 += ak * w4b.x; ex5 += ak * w4b.y; ex6 += ak * w4b.z; ex7 += ak * w4b.w;
    }
    float inv = 1.f / (lden + 1e-16f);
    float4 oA, oB;
    oA.x = (acA.x + ex0) * inv + sk0.x;
    oA.y = (acA.y + ex1) * inv + sk0.y;
    oA.z = (acA.z + ex2) * inv + sk1.x;
    oA.w = (acA.w + ex3) * inv + sk1.y;
    oB.x = (acB.x + ex4) * inv + sk2.x;
    oB.y = (acB.y + ex5) * inv + sk2.y;
    oB.z = (acB.z + ex6) * inv + sk3.x;
    oB.w = (acB.w + ex7) * inv + sk3.y;
    *(float4*)outp = oA;
    *(float4*)(outp + 4) = oB;
}

// ---------------- launch ----------------
extern "C" void kernel_launch(void* const* d_in, const int* in_sizes, int n_in,
                              void* d_out, int out_size, void* d_ws, size_t ws_size,
                              hipStream_t stream)
{
    const float* x  = (const float*)d_in[0];
    const int*   ei = (const int*)d_in[1];
    const float* ea = (const float*)d_in[2];
    const float *Wq1 = (const float*)d_in[3],  *bq1 = (const float*)d_in[4];
    const float *Wk1 = (const float*)d_in[5],  *bk1 = (const float*)d_in[6];
    const float *Wv1 = (const float*)d_in[7],  *bv1 = (const float*)d_in[8];
    const float *We1 = (const float*)d_in[9],  *be1 = (const float*)d_in[10];
    const float *Ws1 = (const float*)d_in[11], *bs1 = (const float*)d_in[12];
    const float *Wq2 = (const float*)d_in[13], *bq2 = (const float*)d_in[14];
    const float *Wk2 = (const float*)d_in[15], *bk2 = (const float*)d_in[16];
    const float *Wv2 = (const float*)d_in[17], *bv2 = (const float*)d_in[18];
    const float *We2 = (const float*)d_in[19], *be2 = (const float*)d_in[20];
    const float *Ws2 = (const float*)d_in[21], *bs2 = (const float*)d_in[22];

    const int N = in_sizes[0] / 128;
    const int E = in_sizes[1] / 2;

    char* ws = (char*)d_ws;
    size_t off = 0;
    auto alloc = [&](size_t bytes) -> void* {
        void* p = ws + off;
        off = (off + bytes + 255) & ~(size_t)255;
        return p;
    };
    unsigned short* xb  = (unsigned short*)alloc((size_t)N * 128 * 2);
    unsigned short* P   = (unsigned short*)alloc((size_t)N * 512 * 2);  // bf16 [kv-interleave | q | s]
    unsigned short* h1b = (unsigned short*)alloc((size_t)N * 128 * 2);
    unsigned short* Wt1 = (unsigned short*)alloc((size_t)640 * 128 * 2);
    unsigned short* Wt2 = (unsigned short*)alloc((size_t)640 * 128 * 2);
    float* bias1 = (float*)alloc(640 * 4);
    float* bias2 = (float*)alloc(640 * 4);
    float* qWe   = (float*)alloc((size_t)N * 128 * 4);
    int*  deg    = (int*)alloc((size_t)N * 4);
    int*  rowptr = (int*)alloc((size_t)(N + 1) * 4);
    int*  cursor = (int*)alloc((size_t)N * 4);
    int*  partial= (int*)alloc(256 * 4);
    int2* csr    = (int2*)alloc((size_t)E * 8);

    dim3 gemm_grid1((N + 63) / 64, 10);
    dim3 gemm_grid2((N + 63) / 64, 9);   // layer-2 qWe needs only cols [512,528)
    const int tn = N * 128;
    const int node_blocks = (N + 15) / 16;   // 16 nodes (16 quarter-waves) per 256-thread block
    const int prep_blocks = (640 * 128 + 255) / 256;
    const int scan_blocks = (N + 255) / 256; // <=256 required (N<=65536)

    // ---- prep (independent of everything else) ----
    convert_x<<<(tn + 255) / 256, 256, 0, stream>>>(x, xb, tn);
    prep_w<<<prep_blocks, 256, 0, stream>>>(Wq1, bq1, Wk1, bk1, Wv1, bv1, be1, Ws1, bs1, We1, 8, Wt1, bias1);
    prep_w<<<prep_blocks, 256, 0, stream>>>(Wq2, bq2, Wk2, bk2, Wv2, bv2, be2, Ws2, bs2, We2, 1, Wt2, bias2);

    // ---- CSR build (shared by both layers) ----
    hipMemsetAsync(deg, 0, (size_t)N * 4, stream);
    hipMemsetAsync(partial, 0, 256 * 4, stream);
    degree_kernel<<<(E + 255) / 256, 256, 0, stream>>>(ei, deg, E);
    scan_part1<<<scan_blocks, 256, 0, stream>>>(deg, partial, N);
    scan_part2<<<1, 256, 0, stream>>>(partial);
    scan_part3<<<scan_blocks, 256, 0, stream>>>(deg, partial, rowptr, cursor, N);
    scatter_kernel<<<(E + 255) / 256, 256, 0, stream>>>(ei, cursor, csr, E);

    // ---- layer 1 (H=8, C=16, concat) ----
    gemm_bf16<<<gemm_grid1, 256, 0, stream>>>(xb, N, Wt1, bias1, P, qWe);
    fused1_node<<<node_blocks, 256, 0, stream>>>(P, qWe, ea, We1, csr, rowptr, h1b, N);

    // ---- layer 2 (H=1, C=128, mean==identity) ----
    gemm_bf16<<<gemm_grid2, 256, 0, stream>>>(h1b, N, Wt2, bias2, P, qWe);
    fused2_node<<<node_blocks, 256, 0, stream>>>(P, qWe, ea, We2, csr, rowptr, (float*)d_out, N);
}